// Round 16
// baseline (805.467 us; speedup 1.0000x reference)
//
#include <hip/hip_runtime.h>
#include <math.h>

#define BATCH 8
#define NPER 2048
#define NPTS (BATCH*NPER)   // 16384
#define KNN 30

typedef __attribute__((ext_vector_type(8))) short bf16x8;
typedef __attribute__((ext_vector_type(4))) float f32x4;

__device__ __forceinline__ ushort f2bf(float x) {
    unsigned u = __float_as_uint(x);
    unsigned r = (u + 0x7fffu + ((u >> 16) & 1u)) >> 16;
    return (ushort)r;
}
__device__ __forceinline__ float bf2f(ushort h) {
    return __uint_as_float(((unsigned)h) << 16);
}

// ---------------- concat x,pos -> x0 (NPTS x 6), fused d2 (sequential order) ----------------
__global__ void concat_d2_kernel(const float* __restrict__ x, const float* __restrict__ pos,
                                 float* __restrict__ x0, float* __restrict__ d2) {
    int n = blockIdx.x * blockDim.x + threadIdx.x;
    if (n >= NPTS) return;
    float v[6];
#pragma unroll
    for (int d = 0; d < 3; ++d) {
        v[d]     = x[n*3 + d];
        v[3 + d] = pos[n*3 + d];
    }
#pragma unroll
    for (int d = 0; d < 6; ++d) x0[n*6 + d] = v[d];
    float s = 0.f;
#pragma unroll
    for (int d = 0; d < 6; ++d) s += v[d]*v[d];
    d2[n] = s;
}

// ---------------- shared selection body: top-30 of one query row (exact top_k ties) ----------
__device__ __forceinline__ void select30(const float* __restrict__ srow, int lane,
                                         int base, int n, int* __restrict__ idx) {
    unsigned u[NPER/64];
#pragma unroll
    for (int i = 0; i < NPER/64; ++i) {
        float dv = srow[lane + 64*i];
        int b = __float_as_int(dv);
        u[i] = (unsigned)(b ^ ((b >> 31) | 0x80000000));
    }

    unsigned T = 0u;
#pragma unroll
    for (int bit = 31; bit >= 0; --bit) {
        unsigned C = T | (1u << bit);
        int c = 0;
#pragma unroll
        for (int i = 0; i < NPER/64; ++i)
            c += (int)__popcll(__ballot(u[i] < C));
        if (c < KNN) T = C;
    }

    unsigned lm = 0u, em = 0u;
#pragma unroll
    for (int i = 0; i < NPER/64; ++i) {
        lm |= (u[i] < T)  ? (1u << i) : 0u;
        em |= (u[i] == T) ? (1u << i) : 0u;
    }
    int nl = __popc(lm);
    int inc = nl;
#pragma unroll
    for (int off = 1; off < 64; off <<= 1) {
        int y = __shfl_up(inc, off);
        if (lane >= off) inc += y;
    }
    int excl = inc - nl;
    int total_less = __shfl(inc, 63);

    int* op = idx + (size_t)n * KNN;
    int slot = excl;
#pragma unroll
    for (int i = 0; i < NPER/64; ++i) {
        if (lm & (1u << i)) { op[slot] = base + i*64 + lane; ++slot; }
    }

    int need = KNN - total_less;
    int running = 0;
#pragma unroll
    for (int i = 0; i < NPER/64; ++i) {
        unsigned long long bal = __ballot((em >> i) & 1u);
        if (bal) {
            unsigned long long lt = bal & ((1ull << lane) - 1ull);
            int r = running + __popcll(lt);
            if (((em >> i) & 1u) && r < need) op[total_less + r] = base + i*64 + lane;
            running += (int)__popcll(bal);
        }
    }
}

// ---------------- kNN (small-D): block = 4 query points; LDS dist + radix select ----------
template<int D>
__global__ __launch_bounds__(256, 4) void knn4_kernel(const float* __restrict__ f, int stride,
                                                      const float* __restrict__ d2,
                                                      int* __restrict__ idx) {
    __shared__ float sdist[4][NPER];      // 32 KB
    __shared__ float sxi[4][(D+3)/4*4];
    __shared__ float sd2n[4];
    int t = threadIdx.x;
    int n0 = blockIdx.x * 4;
    int base = (n0 >> 11) << 11;

    if (t < 4*D) {
        int q = t / D, d = t - q*D;
        sxi[q][d] = f[(size_t)(n0 + q)*stride + d];
    }
    if (t < 4) sd2n[t] = d2[n0 + t];
    __syncthreads();

#pragma unroll 1
    for (int j = 0; j < NPER/256; ++j) {
        int ml = t + 256*j;
        int m = base + ml;
        const float* fm = f + (size_t)m*stride;
        float d2m = d2[m];
        float dot0 = 0.f, dot1 = 0.f, dot2 = 0.f, dot3 = 0.f;
#pragma unroll
        for (int d = 0; d < D; ++d) {
            float a = fm[d];
            dot0 += a*sxi[0][d];
            dot1 += a*sxi[1][d];
            dot2 += a*sxi[2][d];
            dot3 += a*sxi[3][d];
        }
        sdist[0][ml] = sd2n[0] + d2m - 2.f*dot0;
        sdist[1][ml] = sd2n[1] + d2m - 2.f*dot1;
        sdist[2][ml] = sd2n[2] + d2m - 2.f*dot2;
        sdist[3][ml] = sd2n[3] + d2m - 2.f*dot3;
    }
    __syncthreads();

    int w = t >> 6, lane = t & 63;
    select30(sdist[w], lane, base, n0 + w, idx);
}

// ---------------- 64-dim transpose + fused d2 ----------------
__global__ __launch_bounds__(256) void transpose64_kernel(const float* __restrict__ fin, int stride,
                                                          float* __restrict__ fT,
                                                          float* __restrict__ d2out) {
    __shared__ float tile[64][65];
    int t = threadIdx.x;
    int n0 = blockIdx.x * 64;
#pragma unroll
    for (int i = 0; i < 4; ++i) {
        int id = t + 256*i;
        int r = id >> 4, c4 = (id & 15) * 4;
        float4 v = *reinterpret_cast<const float4*>(&fin[(size_t)(n0 + r)*stride + c4]);
        tile[r][c4] = v.x; tile[r][c4+1] = v.y; tile[r][c4+2] = v.z; tile[r][c4+3] = v.w;
    }
    __syncthreads();
    if (t < 64) {
        float s = 0.f;
#pragma unroll
        for (int d = 0; d < 64; ++d) s += tile[t][d]*tile[t][d];
        d2out[n0 + t] = s;
    }
#pragma unroll
    for (int i = 0; i < 16; ++i) {
        int id = t + 256*i;
        int d = id >> 6, nn = id & 63;
        fT[(size_t)d * NPTS + n0 + nn] = tile[nn][d];
    }
}

// ---------------- kNN v7 (D=64): coalesced fT candidates; half-size sdist, two-pass
// ---------------- selection (same values/semantics; 2x occupancy). ----------
__global__ __launch_bounds__(256) void knn6_kernel(const float* __restrict__ fq, int qstride,
                                                   const float* __restrict__ fT,
                                                   const float* __restrict__ d2,
                                                   int* __restrict__ idx) {
    __shared__ float sdist[2][NPER];      // 16 KB (two-pass staging)
    __shared__ float sq[4][64];
    __shared__ float sd2n[4];
    int t = threadIdx.x;
    int n0 = blockIdx.x * 4;
    int base = (n0 >> 11) << 11;

    {
        int q = t >> 6, d = t & 63;
        sq[q][d] = fq[(size_t)(n0 + q)*qstride + d];
    }
    if (t < 4) sd2n[t] = d2[n0 + t];
    __syncthreads();

    float acc0[8], acc1[8], acc2[8], acc3[8];
#pragma unroll
    for (int j = 0; j < 8; ++j) { acc0[j] = 0.f; acc1[j] = 0.f; acc2[j] = 0.f; acc3[j] = 0.f; }

    int cbase = base + 8*t;               // this thread's 8 consecutive candidates

#pragma unroll 2
    for (int dc = 0; dc < 16; ++dc) {
        int d0 = dc * 4;
        float4 q0 = *reinterpret_cast<const float4*>(&sq[0][d0]);
        float4 q1 = *reinterpret_cast<const float4*>(&sq[1][d0]);
        float4 q2 = *reinterpret_cast<const float4*>(&sq[2][d0]);
        float4 q3 = *reinterpret_cast<const float4*>(&sq[3][d0]);
        float qa0[4] = {q0.x, q0.y, q0.z, q0.w};
        float qa1[4] = {q1.x, q1.y, q1.z, q1.w};
        float qa2[4] = {q2.x, q2.y, q2.z, q2.w};
        float qa3[4] = {q3.x, q3.y, q3.z, q3.w};
#pragma unroll
        for (int dd = 0; dd < 4; ++dd) {
            const float* cp = fT + (size_t)(d0 + dd) * NPTS + cbase;
            float4 c0 = *reinterpret_cast<const float4*>(cp);
            float4 c1 = *reinterpret_cast<const float4*>(cp + 4);
            float cv[8] = {c0.x,c0.y,c0.z,c0.w,c1.x,c1.y,c1.z,c1.w};
#pragma unroll
            for (int j = 0; j < 8; ++j) {
                acc0[j] += cv[j]*qa0[dd];
                acc1[j] += cv[j]*qa1[dd];
                acc2[j] += cv[j]*qa2[dd];
                acc3[j] += cv[j]*qa3[dd];
            }
        }
    }

    float4 dm0 = *reinterpret_cast<const float4*>(&d2[cbase]);
    float4 dm1 = *reinterpret_cast<const float4*>(&d2[cbase + 4]);
    float dmv[8] = {dm0.x,dm0.y,dm0.z,dm0.w,dm1.x,dm1.y,dm1.z,dm1.w};

    int w = t >> 6, lane = t & 63;

    // ---- pass A: queries 0,1 ----
    {
        float dn0 = sd2n[0], dn1 = sd2n[1];
#pragma unroll
        for (int j = 0; j < 8; ++j) {
            int ml = 8*t + j;
            sdist[0][ml] = dn0 + dmv[j] - 2.f*acc0[j];
            sdist[1][ml] = dn1 + dmv[j] - 2.f*acc1[j];
        }
    }
    __syncthreads();
    if (w < 2) select30(sdist[w], lane, base, n0 + w, idx);
    __syncthreads();

    // ---- pass B: queries 2,3 ----
    {
        float dn2 = sd2n[2], dn3 = sd2n[3];
#pragma unroll
        for (int j = 0; j < 8; ++j) {
            int ml = 8*t + j;
            sdist[0][ml] = dn2 + dmv[j] - 2.f*acc2[j];
            sdist[1][ml] = dn3 + dmv[j] - 2.f*acc3[j];
        }
    }
    __syncthreads();
    if (w >= 2) select30(sdist[w - 2], lane, base, n0 + w, idx);
}

// ---------------- fused G & Gbase: one sF staging, two passes ----------------
template<int D>
__global__ __launch_bounds__(256) void gmatbase_kernel(const float* __restrict__ fin, int in_stride,
                                                       const float* __restrict__ wa,
                                                       const float* __restrict__ ba,
                                                       float* __restrict__ G,
                                                       float* __restrict__ Gb) {
    constexpr int DP = (D+7)/8*8;
    __shared__ float sF[64][DP];
    int t = threadIdx.x;
    int row0 = blockIdx.x * 64;
    for (int i = t; i < 64*D; i += 256) {
        int r = i / D, c = i - r*D;
        sF[r][c] = fin[(size_t)(row0 + r)*in_stride + c];
    }
    int w = t >> 6, lane = t & 63;
    {
        float wreg[D];
#pragma unroll
        for (int d = 0; d < D; ++d) wreg[d] = wa[(size_t)(D + d)*64 + lane];
        __syncthreads();
#pragma unroll 1
        for (int pi = 0; pi < 16; ++pi) {
            int p = w*16 + pi;
            float acc = 0.f;
            if constexpr (D % 4 == 0) {
#pragma unroll
                for (int d = 0; d < D; d += 4) {
                    float4 fv = *reinterpret_cast<const float4*>(&sF[p][d]);
                    acc += fv.x*wreg[d] + fv.y*wreg[d+1] + fv.z*wreg[d+2] + fv.w*wreg[d+3];
                }
            } else {
#pragma unroll
                for (int d = 0; d < D; ++d) acc += sF[p][d]*wreg[d];
            }
            G[(size_t)(row0 + p)*64 + lane] = acc;
        }
    }
    {
        float wreg[D];
#pragma unroll
        for (int d = 0; d < D; ++d)
            wreg[d] = wa[(size_t)d*64 + lane] - wa[(size_t)(D + d)*64 + lane];
        float bc = ba[lane];
#pragma unroll 1
        for (int pi = 0; pi < 16; ++pi) {
            int p = w*16 + pi;
            float acc = bc;
#pragma unroll
            for (int d = 0; d < D; ++d) acc += sF[p][d]*wreg[d];
            Gb[(size_t)(row0 + p)*64 + lane] = acc;
        }
    }
}

// ---------------- MFMA EdgeConv (emits fp32 + split-bf16 outputs) ----------------
__global__ __launch_bounds__(256) void edgemfma_kernel(
    const float* __restrict__ G, const float* __restrict__ Gbase,
    const int* __restrict__ idx,
    const ushort* __restrict__ wbTh, const ushort* __restrict__ wbTl,
    const float* __restrict__ bb,
    float* __restrict__ fout, int out_stride,
    ushort* __restrict__ fh, ushort* __restrict__ fl)
{
    __shared__ __align__(16) ushort sHh[128*72];
    __shared__ __align__(16) ushort sHl[128*72];
    __shared__ float sbase[4][64];
    int t = threadIdx.x;
    int n0 = blockIdx.x * 4;

    {
        int p = t >> 6, c = t & 63;
        sbase[p][c] = Gbase[(size_t)(n0 + p)*64 + c];
    }
    __syncthreads();

    {
        int r = t >> 1, c0 = (t & 1) * 32;
        int p = r >> 5, e = r & 31;
        int ecl = e < KNN ? e : (KNN - 1);
        int j = idx[(size_t)(n0 + p)*KNN + ecl];
        const float* gp = G + (size_t)j*64 + c0;
        const float* bp = &sbase[p][c0];
#pragma unroll
        for (int g = 0; g < 4; ++g) {
            float4 g0 = *reinterpret_cast<const float4*>(gp + 8*g);
            float4 g1 = *reinterpret_cast<const float4*>(gp + 8*g + 4);
            float4 b0 = *reinterpret_cast<const float4*>(bp + 8*g);
            float4 b1 = *reinterpret_cast<const float4*>(bp + 8*g + 4);
            float h[8] = {fmaxf(b0.x+g0.x,0.f), fmaxf(b0.y+g0.y,0.f),
                          fmaxf(b0.z+g0.z,0.f), fmaxf(b0.w+g0.w,0.f),
                          fmaxf(b1.x+g1.x,0.f), fmaxf(b1.y+g1.y,0.f),
                          fmaxf(b1.z+g1.z,0.f), fmaxf(b1.w+g1.w,0.f)};
            uint ph[4], pl[4];
#pragma unroll
            for (int i2 = 0; i2 < 4; ++i2) {
                ushort h0 = f2bf(h[2*i2]);
                ushort l0 = f2bf(h[2*i2] - bf2f(h0));
                ushort h1_ = f2bf(h[2*i2+1]);
                ushort l1 = f2bf(h[2*i2+1] - bf2f(h1_));
                ph[i2] = (uint)h0 | ((uint)h1_ << 16);
                pl[i2] = (uint)l0 | ((uint)l1 << 16);
            }
            *reinterpret_cast<uint4*>(&sHh[r*72 + c0 + 8*g]) = make_uint4(ph[0],ph[1],ph[2],ph[3]);
            *reinterpret_cast<uint4*>(&sHl[r*72 + c0 + 8*g]) = make_uint4(pl[0],pl[1],pl[2],pl[3]);
        }
    }
    __syncthreads();

    int lane = t & 63, w = t >> 6;
    int fr = lane & 15, fk = (lane >> 4) * 8;

    f32x4 acc[2][4];
#pragma unroll
    for (int mf = 0; mf < 2; ++mf)
#pragma unroll
        for (int nf = 0; nf < 4; ++nf) acc[mf][nf] = f32x4{0.f,0.f,0.f,0.f};

#pragma unroll
    for (int kk = 0; kk < 2; ++kk) {
        bf16x8 a0h = *reinterpret_cast<const bf16x8*>(&sHh[(w*32 + fr)*72 + kk*32 + fk]);
        bf16x8 a1h = *reinterpret_cast<const bf16x8*>(&sHh[(w*32 + 16 + fr)*72 + kk*32 + fk]);
        bf16x8 a0l = *reinterpret_cast<const bf16x8*>(&sHl[(w*32 + fr)*72 + kk*32 + fk]);
        bf16x8 a1l = *reinterpret_cast<const bf16x8*>(&sHl[(w*32 + 16 + fr)*72 + kk*32 + fk]);
#pragma unroll
        for (int nf = 0; nf < 4; ++nf) {
            bf16x8 bh = *reinterpret_cast<const bf16x8*>(&wbTh[(size_t)(nf*16 + fr)*64 + kk*32 + fk]);
            bf16x8 bl = *reinterpret_cast<const bf16x8*>(&wbTl[(size_t)(nf*16 + fr)*64 + kk*32 + fk]);
            acc[0][nf] = __builtin_amdgcn_mfma_f32_16x16x32_bf16(a0h, bh, acc[0][nf], 0,0,0);
            acc[0][nf] = __builtin_amdgcn_mfma_f32_16x16x32_bf16(a0h, bl, acc[0][nf], 0,0,0);
            acc[0][nf] = __builtin_amdgcn_mfma_f32_16x16x32_bf16(a0l, bh, acc[0][nf], 0,0,0);
            acc[1][nf] = __builtin_amdgcn_mfma_f32_16x16x32_bf16(a1h, bh, acc[1][nf], 0,0,0);
            acc[1][nf] = __builtin_amdgcn_mfma_f32_16x16x32_bf16(a1h, bl, acc[1][nf], 0,0,0);
            acc[1][nf] = __builtin_amdgcn_mfma_f32_16x16x32_bf16(a1l, bh, acc[1][nf], 0,0,0);
        }
    }

#pragma unroll
    for (int nf = 0; nf < 4; ++nf) {
        float vmax = -3.4e38f;
#pragma unroll
        for (int mf = 0; mf < 2; ++mf) {
#pragma unroll
            for (int j = 0; j < 4; ++j) {
                int lr = mf*16 + ((lane >> 4) << 2) + j;
                float v = acc[mf][nf][j];
                vmax = (lr < KNN) ? fmaxf(vmax, v) : vmax;
            }
        }
        vmax = fmaxf(vmax, __shfl_xor(vmax, 16));
        vmax = fmaxf(vmax, __shfl_xor(vmax, 32));
        if (lane < 16) {
            int c = nf*16 + lane;
            float v = vmax + bb[c];
            size_t o = (size_t)(n0 + w)*out_stride + c;
            fout[o] = v;
            ushort h = f2bf(v);
            fh[o] = h;
            fl[o] = f2bf(v - bf2f(h));
        }
    }
}

// ---------------- fused weight split: all 6 weight matrices in one dispatch ----------------
__global__ void wsplit_all_kernel(
    const float* __restrict__ hw1, ushort* __restrict__ w1h, ushort* __restrict__ w1l,
    const float* __restrict__ hw2, ushort* __restrict__ w2h, ushort* __restrict__ w2l,
    const float* __restrict__ hw3, ushort* __restrict__ w3h, ushort* __restrict__ w3l,
    const float* __restrict__ w1b, ushort* __restrict__ wb1h, ushort* __restrict__ wb1l,
    const float* __restrict__ w2b, ushort* __restrict__ wb2h, ushort* __restrict__ wb2l,
    const float* __restrict__ w3b, ushort* __restrict__ wb3h, ushort* __restrict__ wb3l)
{
    int gi = blockIdx.x * 256 + threadIdx.x;
    const float* w; ushort* hi; ushort* lo; int K, N, i;
    if (gi < 196608)      { w = hw1; hi = w1h; lo = w1l; K = 192;  N = 1024; i = gi; }
    else if (gi < 720896) { w = hw2; hi = w2h; lo = w2l; K = 1024; N = 512;  i = gi - 196608; }
    else if (gi < 786432) { w = hw3; hi = w3h; lo = w3l; K = 512;  N = 128;  i = gi - 720896; }
    else if (gi < 790528) { w = w1b; hi = wb1h; lo = wb1l; K = 64; N = 64;   i = gi - 786432; }
    else if (gi < 794624) { w = w2b; hi = wb2h; lo = wb2l; K = 64; N = 64;   i = gi - 790528; }
    else if (gi < 798720) { w = w3b; hi = wb3h; lo = wb3l; K = 64; N = 64;   i = gi - 794624; }
    else return;
    int n = i / K, k = i - n*K;
    float x = w[(size_t)k * N + n];
    ushort h = f2bf(x);
    hi[i] = h;
    lo[i] = f2bf(x - bf2f(h));
}

// ---------------- 128x128-tile split-bf16 GEMM: C = act(A @ B^T + bias) ----------------
template<bool RELU, bool SPLIT_OUT>
__global__ __launch_bounds__(256) void mlp_gemm2_kernel(
    const ushort* __restrict__ Ah, const ushort* __restrict__ Al, int K,
    const ushort* __restrict__ Bh, const ushort* __restrict__ Bl,
    const float* __restrict__ bias,
    float* __restrict__ C, ushort* __restrict__ Ch, ushort* __restrict__ Cl, int N)
{
    __shared__ __align__(16) ushort sAh[128*40];
    __shared__ __align__(16) ushort sAl[128*40];
    __shared__ __align__(16) ushort sBh[128*40];
    __shared__ __align__(16) ushort sBl[128*40];
    int t = threadIdx.x;
    int lane = t & 63, w = t >> 6;
    int row0 = blockIdx.x * 128;
    int n0   = blockIdx.y * 128;
    int wr = w & 1, wc = w >> 1;
    int fr = lane & 15, fq = lane >> 4, fk = fq * 8;
    int r = t >> 2, sg = (t & 3) * 8;

    f32x4 acc[4][4];
#pragma unroll
    for (int m = 0; m < 4; ++m)
#pragma unroll
        for (int n = 0; n < 4; ++n) acc[m][n] = f32x4{0.f,0.f,0.f,0.f};

    const int nk = K / 32;
#pragma unroll 1
    for (int kc = 0; kc < nk; ++kc) {
        int k0 = kc * 32;
        uint4 vah0 = *reinterpret_cast<const uint4*>(&Ah[(size_t)(row0 + r)*K + k0 + sg]);
        uint4 vah1 = *reinterpret_cast<const uint4*>(&Ah[(size_t)(row0 + r + 64)*K + k0 + sg]);
        uint4 val0 = *reinterpret_cast<const uint4*>(&Al[(size_t)(row0 + r)*K + k0 + sg]);
        uint4 val1 = *reinterpret_cast<const uint4*>(&Al[(size_t)(row0 + r + 64)*K + k0 + sg]);
        uint4 vbh0 = *reinterpret_cast<const uint4*>(&Bh[(size_t)(n0 + r)*K + k0 + sg]);
        uint4 vbh1 = *reinterpret_cast<const uint4*>(&Bh[(size_t)(n0 + r + 64)*K + k0 + sg]);
        uint4 vbl0 = *reinterpret_cast<const uint4*>(&Bl[(size_t)(n0 + r)*K + k0 + sg]);
        uint4 vbl1 = *reinterpret_cast<const uint4*>(&Bl[(size_t)(n0 + r + 64)*K + k0 + sg]);
        __syncthreads();
        *reinterpret_cast<uint4*>(&sAh[r*40 + sg]) = vah0;
        *reinterpret_cast<uint4*>(&sAh[(r+64)*40 + sg]) = vah1;
        *reinterpret_cast<uint4*>(&sAl[r*40 + sg]) = val0;
        *reinterpret_cast<uint4*>(&sAl[(r+64)*40 + sg]) = val1;
        *reinterpret_cast<uint4*>(&sBh[r*40 + sg]) = vbh0;
        *reinterpret_cast<uint4*>(&sBh[(r+64)*40 + sg]) = vbh1;
        *reinterpret_cast<uint4*>(&sBl[r*40 + sg]) = vbl0;
        *reinterpret_cast<uint4*>(&sBl[(r+64)*40 + sg]) = vbl1;
        __syncthreads();

        bf16x8 bh_[4], bl_[4];
#pragma unroll
        for (int n = 0; n < 4; ++n) {
            bh_[n] = *reinterpret_cast<const bf16x8*>(&sBh[(wc*64 + n*16 + fr)*40 + fk]);
            bl_[n] = *reinterpret_cast<const bf16x8*>(&sBl[(wc*64 + n*16 + fr)*40 + fk]);
        }
#pragma unroll
        for (int m = 0; m < 4; ++m) {
            bf16x8 ah_ = *reinterpret_cast<const bf16x8*>(&sAh[(wr*64 + m*16 + fr)*40 + fk]);
            bf16x8 al_ = *reinterpret_cast<const bf16x8*>(&sAl[(wr*64 + m*16 + fr)*40 + fk]);
#pragma unroll
            for (int n = 0; n < 4; ++n) {
                acc[m][n] = __builtin_amdgcn_mfma_f32_16x16x32_bf16(ah_, bh_[n], acc[m][n], 0,0,0);
                acc[m][n] = __builtin_amdgcn_mfma_f32_16x16x32_bf16(ah_, bl_[n], acc[m][n], 0,0,0);
                acc[m][n] = __builtin_amdgcn_mfma_f32_16x16x32_bf16(al_, bh_[n], acc[m][n], 0,0,0);
            }
        }
    }

#pragma unroll
    for (int n = 0; n < 4; ++n) {
        int ocol = n0 + wc*64 + n*16 + fr;
        float bc = bias[ocol];
#pragma unroll
        for (int m = 0; m < 4; ++m) {
            int orow = row0 + wr*64 + m*16 + fq*4;
#pragma unroll
            for (int j = 0; j < 4; ++j) {
                float v = acc[m][n][j] + bc;
                if (RELU) v = fmaxf(v, 0.f);
                if (SPLIT_OUT) {
                    ushort h = f2bf(v);
                    Ch[(size_t)(orow + j)*N + ocol] = h;
                    Cl[(size_t)(orow + j)*N + ocol] = f2bf(v - bf2f(h));
                } else {
                    C[(size_t)(orow + j)*N + ocol] = v;
                }
            }
        }
    }
}

// ---------------- 64x128-tile variant (for low-grid output layer) ----------------
template<bool RELU>
__global__ __launch_bounds__(256) void mlp_gemm3_kernel(
    const ushort* __restrict__ Ah, const ushort* __restrict__ Al, int K,
    const ushort* __restrict__ Bh, const ushort* __restrict__ Bl,
    const float* __restrict__ bias,
    float* __restrict__ C, int N)
{
    __shared__ __align__(16) ushort sAh[64*40];
    __shared__ __align__(16) ushort sAl[64*40];
    __shared__ __align__(16) ushort sBh[128*40];
    __shared__ __align__(16) ushort sBl[128*40];
    int t = threadIdx.x;
    int lane = t & 63, w = t >> 6;
    int row0 = blockIdx.x * 64;
    int n0   = blockIdx.y * 128;
    int wr = w & 1, wc = w >> 1;
    int fr = lane & 15, fq = lane >> 4, fk = fq * 8;
    int r = t >> 2, sg = (t & 3) * 8;

    f32x4 acc[2][4];
#pragma unroll
    for (int m = 0; m < 2; ++m)
#pragma unroll
        for (int n = 0; n < 4; ++n) acc[m][n] = f32x4{0.f,0.f,0.f,0.f};

    const int nk = K / 32;
#pragma unroll 1
    for (int kc = 0; kc < nk; ++kc) {
        int k0 = kc * 32;
        uint4 vah0 = *reinterpret_cast<const uint4*>(&Ah[(size_t)(row0 + r)*K + k0 + sg]);
        uint4 val0 = *reinterpret_cast<const uint4*>(&Al[(size_t)(row0 + r)*K + k0 + sg]);
        uint4 vbh0 = *reinterpret_cast<const uint4*>(&Bh[(size_t)(n0 + r)*K + k0 + sg]);
        uint4 vbh1 = *reinterpret_cast<const uint4*>(&Bh[(size_t)(n0 + r + 64)*K + k0 + sg]);
        uint4 vbl0 = *reinterpret_cast<const uint4*>(&Bl[(size_t)(n0 + r)*K + k0 + sg]);
        uint4 vbl1 = *reinterpret_cast<const uint4*>(&Bl[(size_t)(n0 + r + 64)*K + k0 + sg]);
        __syncthreads();
        *reinterpret_cast<uint4*>(&sAh[r*40 + sg]) = vah0;
        *reinterpret_cast<uint4*>(&sAl[r*40 + sg]) = val0;
        *reinterpret_cast<uint4*>(&sBh[r*40 + sg]) = vbh0;
        *reinterpret_cast<uint4*>(&sBh[(r+64)*40 + sg]) = vbh1;
        *reinterpret_cast<uint4*>(&sBl[r*40 + sg]) = vbl0;
        *reinterpret_cast<uint4*>(&sBl[(r+64)*40 + sg]) = vbl1;
        __syncthreads();

        bf16x8 bh_[4], bl_[4];
#pragma unroll
        for (int n = 0; n < 4; ++n) {
            bh_[n] = *reinterpret_cast<const bf16x8*>(&sBh[(wc*64 + n*16 + fr)*40 + fk]);
            bl_[n] = *reinterpret_cast<const bf16x8*>(&sBl[(wc*64 + n*16 + fr)*40 + fk]);
        }
#pragma unroll
        for (int m = 0; m < 2; ++m) {
            bf16x8 ah_ = *reinterpret_cast<const bf16x8*>(&sAh[(wr*32 + m*16 + fr)*40 + fk]);
            bf16x8 al_ = *reinterpret_cast<const bf16x8*>(&sAl[(wr*32 + m*16 + fr)*40 + fk]);
#pragma unroll
            for (int n = 0; n < 4; ++n) {
                acc[m][n] = __builtin_amdgcn_mfma_f32_16x16x32_bf16(ah_, bh_[n], acc[m][n], 0,0,0);
                acc[m][n] = __builtin_amdgcn_mfma_f32_16x16x32_bf16(ah_, bl_[n], acc[m][n], 0,0,0);
                acc[m][n] = __builtin_amdgcn_mfma_f32_16x16x32_bf16(al_, bh_[n], acc[m][n], 0,0,0);
            }
        }
    }

#pragma unroll
    for (int n = 0; n < 4; ++n) {
        int ocol = n0 + wc*64 + n*16 + fr;
        float bc = bias[ocol];
#pragma unroll
        for (int m = 0; m < 2; ++m) {
            int orow = row0 + wr*32 + m*16 + fq*4;
#pragma unroll
            for (int j = 0; j < 4; ++j) {
                float v = acc[m][n][j] + bc;
                if (RELU) v = fmaxf(v, 0.f);
                C[(size_t)(orow + j)*N + ocol] = v;
            }
        }
    }
}

extern "C" void kernel_launch(void* const* d_in, const int* in_sizes, int n_in,
                              void* d_out, int out_size, void* d_ws, size_t ws_size,
                              hipStream_t stream) {
    (void)in_sizes; (void)n_in; (void)out_size;
    const float* x   = (const float*)d_in[0];
    const float* pos = (const float*)d_in[1];
    const float* w1a = (const float*)d_in[2];
    const float* b1a = (const float*)d_in[3];
    const float* w1b = (const float*)d_in[4];
    const float* b1b = (const float*)d_in[5];
    const float* w2a = (const float*)d_in[6];
    const float* b2a = (const float*)d_in[7];
    const float* w2b = (const float*)d_in[8];
    const float* b2b = (const float*)d_in[9];
    const float* w3a = (const float*)d_in[10];
    const float* b3a = (const float*)d_in[11];
    const float* w3b = (const float*)d_in[12];
    const float* b3b = (const float*)d_in[13];
    const float* hw1 = (const float*)d_in[14];
    const float* hb1 = (const float*)d_in[15];
    const float* hw2 = (const float*)d_in[16];
    const float* hb2 = (const float*)d_in[17];
    const float* hw3 = (const float*)d_in[18];
    const float* hb3 = (const float*)d_in[19];
    float* out = (float*)d_out;

    float* ws = (float*)d_ws;
    float* x0   = ws;                                  // 98304
    float* feat = ws + 98304;                          // 3145728
    float* d2b  = ws + 3244032;                        // 16384
    int*   idxb = (int*)(ws + 3260416);                // 491520
    float* G    = ws + 3751936;                        // 1048576 (fT before gmatbase, G after)
    ushort* w1h = (ushort*)(ws + 4800512);
    ushort* w1l = (ushort*)(ws + 4898816);
    ushort* w2h = (ushort*)(ws + 4997120);
    ushort* w2l = (ushort*)(ws + 5259264);
    ushort* w3h = (ushort*)(ws + 5521408);
    ushort* w3l = (ushort*)(ws + 5554176);
    ushort* wb1h = (ushort*)(ws + 5586944);
    ushort* wb1l = (ushort*)(ws + 5588992);
    ushort* wb2h = (ushort*)(ws + 5591040);
    ushort* wb2l = (ushort*)(ws + 5593088);
    ushort* wb3h = (ushort*)(ws + 5595136);
    ushort* wb3l = (ushort*)(ws + 5597184);
    float* Gbase = ws + 5599232;                       // 1048576 -> 6647808
    ushort* fAh  = (ushort*)(ws + 6647808);            // -> 8220672
    ushort* fAl  = (ushort*)(ws + 8220672);            // -> 9793536
    const size_t base_units = 9793536;

    float* fT = G;

    int ns = 0;
    {
        const int cands[5] = {1, 2, 4, 8, 16};
        for (int ci = 0; ci < 5; ++ci) {
            int c = cands[ci];
            size_t need = (base_units + (size_t)(NPTS / c) * 1536) * 4;
            if (need <= ws_size) { ns = c; break; }
        }
    }

    wsplit_all_kernel<<<(798720 + 255)/256, 256, 0, stream>>>(
        hw1, w1h, w1l, hw2, w2h, w2l, hw3, w3h, w3l,
        w1b, wb1h, wb1l, w2b, wb2h, wb2l, w3b, wb3h, wb3l);

    concat_d2_kernel<<<NPTS/256, 256, 0, stream>>>(x, pos, x0, d2b);

    // ---- layer 1 (D=6) ----
    knn4_kernel<6><<<NPTS/4, 256, 0, stream>>>(x0, 6, d2b, idxb);
    gmatbase_kernel<6><<<NPTS/64, 256, 0, stream>>>(x0, 6, w1a, b1a, G, Gbase);
    edgemfma_kernel<<<NPTS/4, 256, 0, stream>>>(G, Gbase, idxb, wb1h, wb1l, b1b,
                                                feat, 192, fAh, fAl);

    // ---- layer 2 (D=64) ----
    transpose64_kernel<<<NPTS/64, 256, 0, stream>>>(feat, 192, fT, d2b);
    knn6_kernel<<<NPTS/4, 256, 0, stream>>>(feat, 192, fT, d2b, idxb);
    gmatbase_kernel<64><<<NPTS/64, 256, 0, stream>>>(feat, 192, w2a, b2a, G, Gbase);
    edgemfma_kernel<<<NPTS/4, 256, 0, stream>>>(G, Gbase, idxb, wb2h, wb2l, b2b,
                                                feat + 64, 192, fAh + 64, fAl + 64);

    // ---- layer 3 (D=64) ----
    transpose64_kernel<<<NPTS/64, 256, 0, stream>>>(feat + 64, 192, fT, d2b);
    knn6_kernel<<<NPTS/4, 256, 0, stream>>>(feat + 64, 192, fT, d2b, idxb);
    gmatbase_kernel<64><<<NPTS/64, 256, 0, stream>>>(feat + 64, 192, w3a, b3a, G, Gbase);
    edgemfma_kernel<<<NPTS/4, 256, 0, stream>>>(G, Gbase, idxb, wb3h, wb3l, b3b,
                                                feat + 128, 192, fAh + 128, fAl + 128);

    // ---- head ----
    if (ns > 0) {
        int Ms = NPTS / ns;
        ushort* h1h = (ushort*)(ws + base_units);
        ushort* h1l = h1h + (size_t)Ms * 1024;
        ushort* h2h = (ushort*)(ws + base_units + (size_t)Ms * 1024);
        ushort* h2l = h2h + (size_t)Ms * 512;
        for (int s = 0; s < ns; ++s) {
            const ushort* Ash = fAh + (size_t)s * Ms * 192;
            const ushort* Asl = fAl + (size_t)s * Ms * 192;
            float* outs = out + (size_t)s * Ms * 128;
            mlp_gemm2_kernel<true, true ><<<dim3(Ms/128, 1024/128), 256, 0, stream>>>(
                Ash, Asl, 192, w1h, w1l, hb1, nullptr, h1h, h1l, 1024);
            mlp_gemm2_kernel<true, true ><<<dim3(Ms/128,  512/128), 256, 0, stream>>>(
                h1h, h1l, 1024, w2h, w2l, hb2, nullptr, h2h, h2l, 512);
            mlp_gemm3_kernel<false><<<dim3(Ms/64, 1), 256, 0, stream>>>(
                h2h, h2l, 512, w3h, w3l, hb3, outs, 128);
        }
    }
}

// Round 17
// 680.698 us; speedup vs baseline: 1.1833x; 1.1833x over previous
//
#include <hip/hip_runtime.h>
#include <math.h>

#define BATCH 8
#define NPER 2048
#define NPTS (BATCH*NPER)   // 16384
#define KNN 30

typedef __attribute__((ext_vector_type(8))) short bf16x8;
typedef __attribute__((ext_vector_type(4))) float f32x4;

__device__ __forceinline__ ushort f2bf(float x) {
    unsigned u = __float_as_uint(x);
    unsigned r = (u + 0x7fffu + ((u >> 16) & 1u)) >> 16;
    return (ushort)r;
}
__device__ __forceinline__ float bf2f(ushort h) {
    return __uint_as_float(((unsigned)h) << 16);
}

// ---------------- concat x,pos -> x0 (NPTS x 6), fused d2 (sequential order) ----------------
__global__ void concat_d2_kernel(const float* __restrict__ x, const float* __restrict__ pos,
                                 float* __restrict__ x0, float* __restrict__ d2) {
    int n = blockIdx.x * blockDim.x + threadIdx.x;
    if (n >= NPTS) return;
    float v[6];
#pragma unroll
    for (int d = 0; d < 3; ++d) {
        v[d]     = x[n*3 + d];
        v[3 + d] = pos[n*3 + d];
    }
#pragma unroll
    for (int d = 0; d < 6; ++d) x0[n*6 + d] = v[d];
    float s = 0.f;
#pragma unroll
    for (int d = 0; d < 6; ++d) s += v[d]*v[d];
    d2[n] = s;
}

// ---------------- shared selection body: top-30 of one query row (exact top_k ties) ----------
__device__ __forceinline__ void select30(const float* __restrict__ srow, int lane,
                                         int base, int n, int* __restrict__ idx) {
    unsigned u[NPER/64];
#pragma unroll
    for (int i = 0; i < NPER/64; ++i) {
        float dv = srow[lane + 64*i];
        int b = __float_as_int(dv);
        u[i] = (unsigned)(b ^ ((b >> 31) | 0x80000000));
    }

    unsigned T = 0u;
#pragma unroll
    for (int bit = 31; bit >= 0; --bit) {
        unsigned C = T | (1u << bit);
        int c = 0;
#pragma unroll
        for (int i = 0; i < NPER/64; ++i)
            c += (int)__popcll(__ballot(u[i] < C));
        if (c < KNN) T = C;
    }

    unsigned lm = 0u, em = 0u;
#pragma unroll
    for (int i = 0; i < NPER/64; ++i) {
        lm |= (u[i] < T)  ? (1u << i) : 0u;
        em |= (u[i] == T) ? (1u << i) : 0u;
    }
    int nl = __popc(lm);
    int inc = nl;
#pragma unroll
    for (int off = 1; off < 64; off <<= 1) {
        int y = __shfl_up(inc, off);
        if (lane >= off) inc += y;
    }
    int excl = inc - nl;
    int total_less = __shfl(inc, 63);

    int* op = idx + (size_t)n * KNN;
    int slot = excl;
#pragma unroll
    for (int i = 0; i < NPER/64; ++i) {
        if (lm & (1u << i)) { op[slot] = base + i*64 + lane; ++slot; }
    }

    int need = KNN - total_less;
    int running = 0;
#pragma unroll
    for (int i = 0; i < NPER/64; ++i) {
        unsigned long long bal = __ballot((em >> i) & 1u);
        if (bal) {
            unsigned long long lt = bal & ((1ull << lane) - 1ull);
            int r = running + __popcll(lt);
            if (((em >> i) & 1u) && r < need) op[total_less + r] = base + i*64 + lane;
            running += (int)__popcll(bal);
        }
    }
}

// ---------------- kNN (small-D): block = 4 query points; LDS dist + radix select ----------
template<int D>
__global__ __launch_bounds__(256, 4) void knn4_kernel(const float* __restrict__ f, int stride,
                                                      const float* __restrict__ d2,
                                                      int* __restrict__ idx) {
    __shared__ float sdist[4][NPER];      // 32 KB
    __shared__ float sxi[4][(D+3)/4*4];
    __shared__ float sd2n[4];
    int t = threadIdx.x;
    int n0 = blockIdx.x * 4;
    int base = (n0 >> 11) << 11;

    if (t < 4*D) {
        int q = t / D, d = t - q*D;
        sxi[q][d] = f[(size_t)(n0 + q)*stride + d];
    }
    if (t < 4) sd2n[t] = d2[n0 + t];
    __syncthreads();

#pragma unroll 1
    for (int j = 0; j < NPER/256; ++j) {
        int ml = t + 256*j;
        int m = base + ml;
        const float* fm = f + (size_t)m*stride;
        float d2m = d2[m];
        float dot0 = 0.f, dot1 = 0.f, dot2 = 0.f, dot3 = 0.f;
#pragma unroll
        for (int d = 0; d < D; ++d) {
            float a = fm[d];
            dot0 += a*sxi[0][d];
            dot1 += a*sxi[1][d];
            dot2 += a*sxi[2][d];
            dot3 += a*sxi[3][d];
        }
        sdist[0][ml] = sd2n[0] + d2m - 2.f*dot0;
        sdist[1][ml] = sd2n[1] + d2m - 2.f*dot1;
        sdist[2][ml] = sd2n[2] + d2m - 2.f*dot2;
        sdist[3][ml] = sd2n[3] + d2m - 2.f*dot3;
    }
    __syncthreads();

    int w = t >> 6, lane = t & 63;
    select30(sdist[w], lane, base, n0 + w, idx);
}

// ---------------- 64-dim transpose + fused d2 ----------------
__global__ __launch_bounds__(256) void transpose64_kernel(const float* __restrict__ fin, int stride,
                                                          float* __restrict__ fT,
                                                          float* __restrict__ d2out) {
    __shared__ float tile[64][65];
    int t = threadIdx.x;
    int n0 = blockIdx.x * 64;
#pragma unroll
    for (int i = 0; i < 4; ++i) {
        int id = t + 256*i;
        int r = id >> 4, c4 = (id & 15) * 4;
        float4 v = *reinterpret_cast<const float4*>(&fin[(size_t)(n0 + r)*stride + c4]);
        tile[r][c4] = v.x; tile[r][c4+1] = v.y; tile[r][c4+2] = v.z; tile[r][c4+3] = v.w;
    }
    __syncthreads();
    if (t < 64) {
        float s = 0.f;
#pragma unroll
        for (int d = 0; d < 64; ++d) s += tile[t][d]*tile[t][d];
        d2out[n0 + t] = s;
    }
#pragma unroll
    for (int i = 0; i < 16; ++i) {
        int id = t + 256*i;
        int d = id >> 6, nn = id & 63;
        fT[(size_t)d * NPTS + n0 + nn] = tile[nn][d];
    }
}

// ---------------- kNN v6 (D=64): coalesced fT candidates; radix select (r12 best body) ----
__global__ __launch_bounds__(256) void knn6_kernel(const float* __restrict__ fq, int qstride,
                                                   const float* __restrict__ fT,
                                                   const float* __restrict__ d2,
                                                   int* __restrict__ idx) {
    __shared__ float sdist[4][NPER];      // 32 KB
    __shared__ float sq[4][64];
    __shared__ float sd2n[4];
    int t = threadIdx.x;
    int n0 = blockIdx.x * 4;
    int base = (n0 >> 11) << 11;

    {
        int q = t >> 6, d = t & 63;
        sq[q][d] = fq[(size_t)(n0 + q)*qstride + d];
    }
    if (t < 4) sd2n[t] = d2[n0 + t];
    __syncthreads();

    float acc0[8], acc1[8], acc2[8], acc3[8];
#pragma unroll
    for (int j = 0; j < 8; ++j) { acc0[j] = 0.f; acc1[j] = 0.f; acc2[j] = 0.f; acc3[j] = 0.f; }

    int cbase = base + 8*t;               // this thread's 8 consecutive candidates

#pragma unroll 2
    for (int dc = 0; dc < 16; ++dc) {
        int d0 = dc * 4;
        float4 q0 = *reinterpret_cast<const float4*>(&sq[0][d0]);
        float4 q1 = *reinterpret_cast<const float4*>(&sq[1][d0]);
        float4 q2 = *reinterpret_cast<const float4*>(&sq[2][d0]);
        float4 q3 = *reinterpret_cast<const float4*>(&sq[3][d0]);
        float qa0[4] = {q0.x, q0.y, q0.z, q0.w};
        float qa1[4] = {q1.x, q1.y, q1.z, q1.w};
        float qa2[4] = {q2.x, q2.y, q2.z, q2.w};
        float qa3[4] = {q3.x, q3.y, q3.z, q3.w};
#pragma unroll
        for (int dd = 0; dd < 4; ++dd) {
            const float* cp = fT + (size_t)(d0 + dd) * NPTS + cbase;
            float4 c0 = *reinterpret_cast<const float4*>(cp);
            float4 c1 = *reinterpret_cast<const float4*>(cp + 4);
            float cv[8] = {c0.x,c0.y,c0.z,c0.w,c1.x,c1.y,c1.z,c1.w};
#pragma unroll
            for (int j = 0; j < 8; ++j) {
                acc0[j] += cv[j]*qa0[dd];
                acc1[j] += cv[j]*qa1[dd];
                acc2[j] += cv[j]*qa2[dd];
                acc3[j] += cv[j]*qa3[dd];
            }
        }
    }

    {
        float dn0 = sd2n[0], dn1 = sd2n[1], dn2 = sd2n[2], dn3 = sd2n[3];
        float4 dm0 = *reinterpret_cast<const float4*>(&d2[cbase]);
        float4 dm1 = *reinterpret_cast<const float4*>(&d2[cbase + 4]);
        float dmv[8] = {dm0.x,dm0.y,dm0.z,dm0.w,dm1.x,dm1.y,dm1.z,dm1.w};
#pragma unroll
        for (int j = 0; j < 8; ++j) {
            int ml = 8*t + j;
            sdist[0][ml] = dn0 + dmv[j] - 2.f*acc0[j];
            sdist[1][ml] = dn1 + dmv[j] - 2.f*acc1[j];
            sdist[2][ml] = dn2 + dmv[j] - 2.f*acc2[j];
            sdist[3][ml] = dn3 + dmv[j] - 2.f*acc3[j];
        }
    }
    __syncthreads();

    int w = t >> 6, lane = t & 63;
    select30(sdist[w], lane, base, n0 + w, idx);
}

// ---------------- fused G & Gbase: one sF staging, two passes ----------------
template<int D>
__global__ __launch_bounds__(256) void gmatbase_kernel(const float* __restrict__ fin, int in_stride,
                                                       const float* __restrict__ wa,
                                                       const float* __restrict__ ba,
                                                       float* __restrict__ G,
                                                       float* __restrict__ Gb) {
    constexpr int DP = (D+7)/8*8;
    __shared__ float sF[64][DP];
    int t = threadIdx.x;
    int row0 = blockIdx.x * 64;
    for (int i = t; i < 64*D; i += 256) {
        int r = i / D, c = i - r*D;
        sF[r][c] = fin[(size_t)(row0 + r)*in_stride + c];
    }
    int w = t >> 6, lane = t & 63;
    {
        float wreg[D];
#pragma unroll
        for (int d = 0; d < D; ++d) wreg[d] = wa[(size_t)(D + d)*64 + lane];
        __syncthreads();
#pragma unroll 1
        for (int pi = 0; pi < 16; ++pi) {
            int p = w*16 + pi;
            float acc = 0.f;
            if constexpr (D % 4 == 0) {
#pragma unroll
                for (int d = 0; d < D; d += 4) {
                    float4 fv = *reinterpret_cast<const float4*>(&sF[p][d]);
                    acc += fv.x*wreg[d] + fv.y*wreg[d+1] + fv.z*wreg[d+2] + fv.w*wreg[d+3];
                }
            } else {
#pragma unroll
                for (int d = 0; d < D; ++d) acc += sF[p][d]*wreg[d];
            }
            G[(size_t)(row0 + p)*64 + lane] = acc;
        }
    }
    {
        float wreg[D];
#pragma unroll
        for (int d = 0; d < D; ++d)
            wreg[d] = wa[(size_t)d*64 + lane] - wa[(size_t)(D + d)*64 + lane];
        float bc = ba[lane];
#pragma unroll 1
        for (int pi = 0; pi < 16; ++pi) {
            int p = w*16 + pi;
            float acc = bc;
#pragma unroll
            for (int d = 0; d < D; ++d) acc += sF[p][d]*wreg[d];
            Gb[(size_t)(row0 + p)*64 + lane] = acc;
        }
    }
}

// ---------------- MFMA EdgeConv (emits fp32 + split-bf16 outputs) ----------------
__global__ __launch_bounds__(256) void edgemfma_kernel(
    const float* __restrict__ G, const float* __restrict__ Gbase,
    const int* __restrict__ idx,
    const ushort* __restrict__ wbTh, const ushort* __restrict__ wbTl,
    const float* __restrict__ bb,
    float* __restrict__ fout, int out_stride,
    ushort* __restrict__ fh, ushort* __restrict__ fl)
{
    __shared__ __align__(16) ushort sHh[128*72];
    __shared__ __align__(16) ushort sHl[128*72];
    __shared__ float sbase[4][64];
    int t = threadIdx.x;
    int n0 = blockIdx.x * 4;

    {
        int p = t >> 6, c = t & 63;
        sbase[p][c] = Gbase[(size_t)(n0 + p)*64 + c];
    }
    __syncthreads();

    {
        int r = t >> 1, c0 = (t & 1) * 32;
        int p = r >> 5, e = r & 31;
        int ecl = e < KNN ? e : (KNN - 1);
        int j = idx[(size_t)(n0 + p)*KNN + ecl];
        const float* gp = G + (size_t)j*64 + c0;
        const float* bp = &sbase[p][c0];
#pragma unroll
        for (int g = 0; g < 4; ++g) {
            float4 g0 = *reinterpret_cast<const float4*>(gp + 8*g);
            float4 g1 = *reinterpret_cast<const float4*>(gp + 8*g + 4);
            float4 b0 = *reinterpret_cast<const float4*>(bp + 8*g);
            float4 b1 = *reinterpret_cast<const float4*>(bp + 8*g + 4);
            float h[8] = {fmaxf(b0.x+g0.x,0.f), fmaxf(b0.y+g0.y,0.f),
                          fmaxf(b0.z+g0.z,0.f), fmaxf(b0.w+g0.w,0.f),
                          fmaxf(b1.x+g1.x,0.f), fmaxf(b1.y+g1.y,0.f),
                          fmaxf(b1.z+g1.z,0.f), fmaxf(b1.w+g1.w,0.f)};
            uint ph[4], pl[4];
#pragma unroll
            for (int i2 = 0; i2 < 4; ++i2) {
                ushort h0 = f2bf(h[2*i2]);
                ushort l0 = f2bf(h[2*i2] - bf2f(h0));
                ushort h1_ = f2bf(h[2*i2+1]);
                ushort l1 = f2bf(h[2*i2+1] - bf2f(h1_));
                ph[i2] = (uint)h0 | ((uint)h1_ << 16);
                pl[i2] = (uint)l0 | ((uint)l1 << 16);
            }
            *reinterpret_cast<uint4*>(&sHh[r*72 + c0 + 8*g]) = make_uint4(ph[0],ph[1],ph[2],ph[3]);
            *reinterpret_cast<uint4*>(&sHl[r*72 + c0 + 8*g]) = make_uint4(pl[0],pl[1],pl[2],pl[3]);
        }
    }
    __syncthreads();

    int lane = t & 63, w = t >> 6;
    int fr = lane & 15, fk = (lane >> 4) * 8;

    f32x4 acc[2][4];
#pragma unroll
    for (int mf = 0; mf < 2; ++mf)
#pragma unroll
        for (int nf = 0; nf < 4; ++nf) acc[mf][nf] = f32x4{0.f,0.f,0.f,0.f};

#pragma unroll
    for (int kk = 0; kk < 2; ++kk) {
        bf16x8 a0h = *reinterpret_cast<const bf16x8*>(&sHh[(w*32 + fr)*72 + kk*32 + fk]);
        bf16x8 a1h = *reinterpret_cast<const bf16x8*>(&sHh[(w*32 + 16 + fr)*72 + kk*32 + fk]);
        bf16x8 a0l = *reinterpret_cast<const bf16x8*>(&sHl[(w*32 + fr)*72 + kk*32 + fk]);
        bf16x8 a1l = *reinterpret_cast<const bf16x8*>(&sHl[(w*32 + 16 + fr)*72 + kk*32 + fk]);
#pragma unroll
        for (int nf = 0; nf < 4; ++nf) {
            bf16x8 bh = *reinterpret_cast<const bf16x8*>(&wbTh[(size_t)(nf*16 + fr)*64 + kk*32 + fk]);
            bf16x8 bl = *reinterpret_cast<const bf16x8*>(&wbTl[(size_t)(nf*16 + fr)*64 + kk*32 + fk]);
            acc[0][nf] = __builtin_amdgcn_mfma_f32_16x16x32_bf16(a0h, bh, acc[0][nf], 0,0,0);
            acc[0][nf] = __builtin_amdgcn_mfma_f32_16x16x32_bf16(a0h, bl, acc[0][nf], 0,0,0);
            acc[0][nf] = __builtin_amdgcn_mfma_f32_16x16x32_bf16(a0l, bh, acc[0][nf], 0,0,0);
            acc[1][nf] = __builtin_amdgcn_mfma_f32_16x16x32_bf16(a1h, bh, acc[1][nf], 0,0,0);
            acc[1][nf] = __builtin_amdgcn_mfma_f32_16x16x32_bf16(a1h, bl, acc[1][nf], 0,0,0);
            acc[1][nf] = __builtin_amdgcn_mfma_f32_16x16x32_bf16(a1l, bh, acc[1][nf], 0,0,0);
        }
    }

#pragma unroll
    for (int nf = 0; nf < 4; ++nf) {
        float vmax = -3.4e38f;
#pragma unroll
        for (int mf = 0; mf < 2; ++mf) {
#pragma unroll
            for (int j = 0; j < 4; ++j) {
                int lr = mf*16 + ((lane >> 4) << 2) + j;
                float v = acc[mf][nf][j];
                vmax = (lr < KNN) ? fmaxf(vmax, v) : vmax;
            }
        }
        vmax = fmaxf(vmax, __shfl_xor(vmax, 16));
        vmax = fmaxf(vmax, __shfl_xor(vmax, 32));
        if (lane < 16) {
            int c = nf*16 + lane;
            float v = vmax + bb[c];
            size_t o = (size_t)(n0 + w)*out_stride + c;
            fout[o] = v;
            ushort h = f2bf(v);
            fh[o] = h;
            fl[o] = f2bf(v - bf2f(h));
        }
    }
}

// ---------------- fused weight split: all 6 weight matrices in one dispatch ----------------
__global__ void wsplit_all_kernel(
    const float* __restrict__ hw1, ushort* __restrict__ w1h, ushort* __restrict__ w1l,
    const float* __restrict__ hw2, ushort* __restrict__ w2h, ushort* __restrict__ w2l,
    const float* __restrict__ hw3, ushort* __restrict__ w3h, ushort* __restrict__ w3l,
    const float* __restrict__ w1b, ushort* __restrict__ wb1h, ushort* __restrict__ wb1l,
    const float* __restrict__ w2b, ushort* __restrict__ wb2h, ushort* __restrict__ wb2l,
    const float* __restrict__ w3b, ushort* __restrict__ wb3h, ushort* __restrict__ wb3l)
{
    int gi = blockIdx.x * 256 + threadIdx.x;
    const float* w; ushort* hi; ushort* lo; int K, N, i;
    if (gi < 196608)      { w = hw1; hi = w1h; lo = w1l; K = 192;  N = 1024; i = gi; }
    else if (gi < 720896) { w = hw2; hi = w2h; lo = w2l; K = 1024; N = 512;  i = gi - 196608; }
    else if (gi < 786432) { w = hw3; hi = w3h; lo = w3l; K = 512;  N = 128;  i = gi - 720896; }
    else if (gi < 790528) { w = w1b; hi = wb1h; lo = wb1l; K = 64; N = 64;   i = gi - 786432; }
    else if (gi < 794624) { w = w2b; hi = wb2h; lo = wb2l; K = 64; N = 64;   i = gi - 790528; }
    else if (gi < 798720) { w = w3b; hi = wb3h; lo = wb3l; K = 64; N = 64;   i = gi - 794624; }
    else return;
    int n = i / K, k = i - n*K;
    float x = w[(size_t)k * N + n];
    ushort h = f2bf(x);
    hi[i] = h;
    lo[i] = f2bf(x - bf2f(h));
}

// ---------------- 128x128-tile split-bf16 GEMM: C = act(A @ B^T + bias) ----------------
template<bool RELU, bool SPLIT_OUT>
__global__ __launch_bounds__(256) void mlp_gemm2_kernel(
    const ushort* __restrict__ Ah, const ushort* __restrict__ Al, int K,
    const ushort* __restrict__ Bh, const ushort* __restrict__ Bl,
    const float* __restrict__ bias,
    float* __restrict__ C, ushort* __restrict__ Ch, ushort* __restrict__ Cl, int N)
{
    __shared__ __align__(16) ushort sAh[128*40];
    __shared__ __align__(16) ushort sAl[128*40];
    __shared__ __align__(16) ushort sBh[128*40];
    __shared__ __align__(16) ushort sBl[128*40];
    int t = threadIdx.x;
    int lane = t & 63, w = t >> 6;
    int row0 = blockIdx.x * 128;
    int n0   = blockIdx.y * 128;
    int wr = w & 1, wc = w >> 1;
    int fr = lane & 15, fq = lane >> 4, fk = fq * 8;
    int r = t >> 2, sg = (t & 3) * 8;

    f32x4 acc[4][4];
#pragma unroll
    for (int m = 0; m < 4; ++m)
#pragma unroll
        for (int n = 0; n < 4; ++n) acc[m][n] = f32x4{0.f,0.f,0.f,0.f};

    const int nk = K / 32;
#pragma unroll 1
    for (int kc = 0; kc < nk; ++kc) {
        int k0 = kc * 32;
        uint4 vah0 = *reinterpret_cast<const uint4*>(&Ah[(size_t)(row0 + r)*K + k0 + sg]);
        uint4 vah1 = *reinterpret_cast<const uint4*>(&Ah[(size_t)(row0 + r + 64)*K + k0 + sg]);
        uint4 val0 = *reinterpret_cast<const uint4*>(&Al[(size_t)(row0 + r)*K + k0 + sg]);
        uint4 val1 = *reinterpret_cast<const uint4*>(&Al[(size_t)(row0 + r + 64)*K + k0 + sg]);
        uint4 vbh0 = *reinterpret_cast<const uint4*>(&Bh[(size_t)(n0 + r)*K + k0 + sg]);
        uint4 vbh1 = *reinterpret_cast<const uint4*>(&Bh[(size_t)(n0 + r + 64)*K + k0 + sg]);
        uint4 vbl0 = *reinterpret_cast<const uint4*>(&Bl[(size_t)(n0 + r)*K + k0 + sg]);
        uint4 vbl1 = *reinterpret_cast<const uint4*>(&Bl[(size_t)(n0 + r + 64)*K + k0 + sg]);
        __syncthreads();
        *reinterpret_cast<uint4*>(&sAh[r*40 + sg]) = vah0;
        *reinterpret_cast<uint4*>(&sAh[(r+64)*40 + sg]) = vah1;
        *reinterpret_cast<uint4*>(&sAl[r*40 + sg]) = val0;
        *reinterpret_cast<uint4*>(&sAl[(r+64)*40 + sg]) = val1;
        *reinterpret_cast<uint4*>(&sBh[r*40 + sg]) = vbh0;
        *reinterpret_cast<uint4*>(&sBh[(r+64)*40 + sg]) = vbh1;
        *reinterpret_cast<uint4*>(&sBl[r*40 + sg]) = vbl0;
        *reinterpret_cast<uint4*>(&sBl[(r+64)*40 + sg]) = vbl1;
        __syncthreads();

        bf16x8 bh_[4], bl_[4];
#pragma unroll
        for (int n = 0; n < 4; ++n) {
            bh_[n] = *reinterpret_cast<const bf16x8*>(&sBh[(wc*64 + n*16 + fr)*40 + fk]);
            bl_[n] = *reinterpret_cast<const bf16x8*>(&sBl[(wc*64 + n*16 + fr)*40 + fk]);
        }
#pragma unroll
        for (int m = 0; m < 4; ++m) {
            bf16x8 ah_ = *reinterpret_cast<const bf16x8*>(&sAh[(wr*64 + m*16 + fr)*40 + fk]);
            bf16x8 al_ = *reinterpret_cast<const bf16x8*>(&sAl[(wr*64 + m*16 + fr)*40 + fk]);
#pragma unroll
            for (int n = 0; n < 4; ++n) {
                acc[m][n] = __builtin_amdgcn_mfma_f32_16x16x32_bf16(ah_, bh_[n], acc[m][n], 0,0,0);
                acc[m][n] = __builtin_amdgcn_mfma_f32_16x16x32_bf16(ah_, bl_[n], acc[m][n], 0,0,0);
                acc[m][n] = __builtin_amdgcn_mfma_f32_16x16x32_bf16(al_, bh_[n], acc[m][n], 0,0,0);
            }
        }
    }

#pragma unroll
    for (int n = 0; n < 4; ++n) {
        int ocol = n0 + wc*64 + n*16 + fr;
        float bc = bias[ocol];
#pragma unroll
        for (int m = 0; m < 4; ++m) {
            int orow = row0 + wr*64 + m*16 + fq*4;
#pragma unroll
            for (int j = 0; j < 4; ++j) {
                float v = acc[m][n][j] + bc;
                if (RELU) v = fmaxf(v, 0.f);
                if (SPLIT_OUT) {
                    ushort h = f2bf(v);
                    Ch[(size_t)(orow + j)*N + ocol] = h;
                    Cl[(size_t)(orow + j)*N + ocol] = f2bf(v - bf2f(h));
                } else {
                    C[(size_t)(orow + j)*N + ocol] = v;
                }
            }
        }
    }
}

// ---------------- 64x128-tile variant (for low-grid output layer) ----------------
template<bool RELU>
__global__ __launch_bounds__(256) void mlp_gemm3_kernel(
    const ushort* __restrict__ Ah, const ushort* __restrict__ Al, int K,
    const ushort* __restrict__ Bh, const ushort* __restrict__ Bl,
    const float* __restrict__ bias,
    float* __restrict__ C, int N)
{
    __shared__ __align__(16) ushort sAh[64*40];
    __shared__ __align__(16) ushort sAl[64*40];
    __shared__ __align__(16) ushort sBh[128*40];
    __shared__ __align__(16) ushort sBl[128*40];
    int t = threadIdx.x;
    int lane = t & 63, w = t >> 6;
    int row0 = blockIdx.x * 64;
    int n0   = blockIdx.y * 128;
    int wr = w & 1, wc = w >> 1;
    int fr = lane & 15, fq = lane >> 4, fk = fq * 8;
    int r = t >> 2, sg = (t & 3) * 8;

    f32x4 acc[2][4];
#pragma unroll
    for (int m = 0; m < 2; ++m)
#pragma unroll
        for (int n = 0; n < 4; ++n) acc[m][n] = f32x4{0.f,0.f,0.f,0.f};

    const int nk = K / 32;
#pragma unroll 1
    for (int kc = 0; kc < nk; ++kc) {
        int k0 = kc * 32;
        uint4 vah0 = *reinterpret_cast<const uint4*>(&Ah[(size_t)(row0 + r)*K + k0 + sg]);
        uint4 val0 = *reinterpret_cast<const uint4*>(&Al[(size_t)(row0 + r)*K + k0 + sg]);
        uint4 vbh0 = *reinterpret_cast<const uint4*>(&Bh[(size_t)(n0 + r)*K + k0 + sg]);
        uint4 vbh1 = *reinterpret_cast<const uint4*>(&Bh[(size_t)(n0 + r + 64)*K + k0 + sg]);
        uint4 vbl0 = *reinterpret_cast<const uint4*>(&Bl[(size_t)(n0 + r)*K + k0 + sg]);
        uint4 vbl1 = *reinterpret_cast<const uint4*>(&Bl[(size_t)(n0 + r + 64)*K + k0 + sg]);
        __syncthreads();
        *reinterpret_cast<uint4*>(&sAh[r*40 + sg]) = vah0;
        *reinterpret_cast<uint4*>(&sAl[r*40 + sg]) = val0;
        *reinterpret_cast<uint4*>(&sBh[r*40 + sg]) = vbh0;
        *reinterpret_cast<uint4*>(&sBh[(r+64)*40 + sg]) = vbh1;
        *reinterpret_cast<uint4*>(&sBl[r*40 + sg]) = vbl0;
        *reinterpret_cast<uint4*>(&sBl[(r+64)*40 + sg]) = vbl1;
        __syncthreads();

        bf16x8 bh_[4], bl_[4];
#pragma unroll
        for (int n = 0; n < 4; ++n) {
            bh_[n] = *reinterpret_cast<const bf16x8*>(&sBh[(wc*64 + n*16 + fr)*40 + fk]);
            bl_[n] = *reinterpret_cast<const bf16x8*>(&sBl[(wc*64 + n*16 + fr)*40 + fk]);
        }
#pragma unroll
        for (int m = 0; m < 2; ++m) {
            bf16x8 ah_ = *reinterpret_cast<const bf16x8*>(&sAh[(wr*32 + m*16 + fr)*40 + fk]);
            bf16x8 al_ = *reinterpret_cast<const bf16x8*>(&sAl[(wr*32 + m*16 + fr)*40 + fk]);
#pragma unroll
            for (int n = 0; n < 4; ++n) {
                acc[m][n] = __builtin_amdgcn_mfma_f32_16x16x32_bf16(ah_, bh_[n], acc[m][n], 0,0,0);
                acc[m][n] = __builtin_amdgcn_mfma_f32_16x16x32_bf16(ah_, bl_[n], acc[m][n], 0,0,0);
                acc[m][n] = __builtin_amdgcn_mfma_f32_16x16x32_bf16(al_, bh_[n], acc[m][n], 0,0,0);
            }
        }
    }

#pragma unroll
    for (int n = 0; n < 4; ++n) {
        int ocol = n0 + wc*64 + n*16 + fr;
        float bc = bias[ocol];
#pragma unroll
        for (int m = 0; m < 2; ++m) {
            int orow = row0 + wr*32 + m*16 + fq*4;
#pragma unroll
            for (int j = 0; j < 4; ++j) {
                float v = acc[m][n][j] + bc;
                if (RELU) v = fmaxf(v, 0.f);
                C[(size_t)(orow + j)*N + ocol] = v;
            }
        }
    }
}

extern "C" void kernel_launch(void* const* d_in, const int* in_sizes, int n_in,
                              void* d_out, int out_size, void* d_ws, size_t ws_size,
                              hipStream_t stream) {
    (void)in_sizes; (void)n_in; (void)out_size;
    const float* x   = (const float*)d_in[0];
    const float* pos = (const float*)d_in[1];
    const float* w1a = (const float*)d_in[2];
    const float* b1a = (const float*)d_in[3];
    const float* w1b = (const float*)d_in[4];
    const float* b1b = (const float*)d_in[5];
    const float* w2a = (const float*)d_in[6];
    const float* b2a = (const float*)d_in[7];
    const float* w2b = (const float*)d_in[8];
    const float* b2b = (const float*)d_in[9];
    const float* w3a = (const float*)d_in[10];
    const float* b3a = (const float*)d_in[11];
    const float* w3b = (const float*)d_in[12];
    const float* b3b = (const float*)d_in[13];
    const float* hw1 = (const float*)d_in[14];
    const float* hb1 = (const float*)d_in[15];
    const float* hw2 = (const float*)d_in[16];
    const float* hb2 = (const float*)d_in[17];
    const float* hw3 = (const float*)d_in[18];
    const float* hb3 = (const float*)d_in[19];
    float* out = (float*)d_out;

    float* ws = (float*)d_ws;
    float* x0   = ws;                                  // 98304
    float* feat = ws + 98304;                          // 3145728
    float* d2b  = ws + 3244032;                        // 16384
    int*   idxb = (int*)(ws + 3260416);                // 491520
    float* G    = ws + 3751936;                        // 1048576 (fT before gmatbase, G after)
    ushort* w1h = (ushort*)(ws + 4800512);
    ushort* w1l = (ushort*)(ws + 4898816);
    ushort* w2h = (ushort*)(ws + 4997120);
    ushort* w2l = (ushort*)(ws + 5259264);
    ushort* w3h = (ushort*)(ws + 5521408);
    ushort* w3l = (ushort*)(ws + 5554176);
    ushort* wb1h = (ushort*)(ws + 5586944);
    ushort* wb1l = (ushort*)(ws + 5588992);
    ushort* wb2h = (ushort*)(ws + 5591040);
    ushort* wb2l = (ushort*)(ws + 5593088);
    ushort* wb3h = (ushort*)(ws + 5595136);
    ushort* wb3l = (ushort*)(ws + 5597184);
    float* Gbase = ws + 5599232;                       // 1048576 -> 6647808
    ushort* fAh  = (ushort*)(ws + 6647808);            // -> 8220672
    ushort* fAl  = (ushort*)(ws + 8220672);            // -> 9793536
    const size_t base_units = 9793536;

    float* fT = G;

    int ns = 0;
    {
        const int cands[5] = {1, 2, 4, 8, 16};
        for (int ci = 0; ci < 5; ++ci) {
            int c = cands[ci];
            size_t need = (base_units + (size_t)(NPTS / c) * 1536) * 4;
            if (need <= ws_size) { ns = c; break; }
        }
    }

    wsplit_all_kernel<<<(798720 + 255)/256, 256, 0, stream>>>(
        hw1, w1h, w1l, hw2, w2h, w2l, hw3, w3h, w3l,
        w1b, wb1h, wb1l, w2b, wb2h, wb2l, w3b, wb3h, wb3l);

    concat_d2_kernel<<<NPTS/256, 256, 0, stream>>>(x, pos, x0, d2b);

    // ---- layer 1 (D=6) ----
    knn4_kernel<6><<<NPTS/4, 256, 0, stream>>>(x0, 6, d2b, idxb);
    gmatbase_kernel<6><<<NPTS/64, 256, 0, stream>>>(x0, 6, w1a, b1a, G, Gbase);
    edgemfma_kernel<<<NPTS/4, 256, 0, stream>>>(G, Gbase, idxb, wb1h, wb1l, b1b,
                                                feat, 192, fAh, fAl);

    // ---- layer 2 (D=64) ----
    transpose64_kernel<<<NPTS/64, 256, 0, stream>>>(feat, 192, fT, d2b);
    knn6_kernel<<<NPTS/4, 256, 0, stream>>>(feat, 192, fT, d2b, idxb);
    gmatbase_kernel<64><<<NPTS/64, 256, 0, stream>>>(feat, 192, w2a, b2a, G, Gbase);
    edgemfma_kernel<<<NPTS/4, 256, 0, stream>>>(G, Gbase, idxb, wb2h, wb2l, b2b,
                                                feat + 64, 192, fAh + 64, fAl + 64);

    // ---- layer 3 (D=64) ----
    transpose64_kernel<<<NPTS/64, 256, 0, stream>>>(feat + 64, 192, fT, d2b);
    knn6_kernel<<<NPTS/4, 256, 0, stream>>>(feat + 64, 192, fT, d2b, idxb);
    gmatbase_kernel<64><<<NPTS/64, 256, 0, stream>>>(feat + 64, 192, w3a, b3a, G, Gbase);
    edgemfma_kernel<<<NPTS/4, 256, 0, stream>>>(G, Gbase, idxb, wb3h, wb3l, b3b,
                                                feat + 128, 192, fAh + 128, fAl + 128);

    // ---- head ----
    if (ns > 0) {
        int Ms = NPTS / ns;
        ushort* h1h = (ushort*)(ws + base_units);
        ushort* h1l = h1h + (size_t)Ms * 1024;
        ushort* h2h = (ushort*)(ws + base_units + (size_t)Ms * 1024);
        ushort* h2l = h2h + (size_t)Ms * 512;
        for (int s = 0; s < ns; ++s) {
            const ushort* Ash = fAh + (size_t)s * Ms * 192;
            const ushort* Asl = fAl + (size_t)s * Ms * 192;
            float* outs = out + (size_t)s * Ms * 128;
            mlp_gemm2_kernel<true, true ><<<dim3(Ms/128, 1024/128), 256, 0, stream>>>(
                Ash, Asl, 192, w1h, w1l, hb1, nullptr, h1h, h1l, 1024);
            mlp_gemm2_kernel<true, true ><<<dim3(Ms/128,  512/128), 256, 0, stream>>>(
                h1h, h1l, 1024, w2h, w2l, hb2, nullptr, h2h, h2l, 512);
            mlp_gemm3_kernel<false><<<dim3(Ms/64, 1), 256, 0, stream>>>(
                h2h, h2l, 512, w3h, w3l, hb3, outs, 128);
        }
    }
}

// Round 18
// 665.482 us; speedup vs baseline: 1.2104x; 1.0229x over previous
//
#include <hip/hip_runtime.h>
#include <math.h>

#define BATCH 8
#define NPER 2048
#define NPTS (BATCH*NPER)   // 16384
#define KNN 30

typedef __attribute__((ext_vector_type(8))) short bf16x8;
typedef __attribute__((ext_vector_type(4))) float f32x4;

__device__ __forceinline__ ushort f2bf(float x) {
    unsigned u = __float_as_uint(x);
    unsigned r = (u + 0x7fffu + ((u >> 16) & 1u)) >> 16;
    return (ushort)r;
}
__device__ __forceinline__ float bf2f(ushort h) {
    return __uint_as_float(((unsigned)h) << 16);
}

// ---------------- concat x,pos -> x0 (NPTS x 6), fused d2 (sequential order) ----------------
__global__ void concat_d2_kernel(const float* __restrict__ x, const float* __restrict__ pos,
                                 float* __restrict__ x0, float* __restrict__ d2) {
    int n = blockIdx.x * blockDim.x + threadIdx.x;
    if (n >= NPTS) return;
    float v[6];
#pragma unroll
    for (int d = 0; d < 3; ++d) {
        v[d]     = x[n*3 + d];
        v[3 + d] = pos[n*3 + d];
    }
#pragma unroll
    for (int d = 0; d < 6; ++d) x0[n*6 + d] = v[d];
    float s = 0.f;
#pragma unroll
    for (int d = 0; d < 6; ++d) s += v[d]*v[d];
    d2[n] = s;
}

// ---------------- shared selection body: top-30 of one query row (exact top_k ties) ----------
__device__ __forceinline__ void select30(const float* __restrict__ srow, int lane,
                                         int base, int n, int* __restrict__ idx) {
    unsigned u[NPER/64];
#pragma unroll
    for (int i = 0; i < NPER/64; ++i) {
        float dv = srow[lane + 64*i];
        int b = __float_as_int(dv);
        u[i] = (unsigned)(b ^ ((b >> 31) | 0x80000000));
    }

    unsigned T = 0u;
#pragma unroll
    for (int bit = 31; bit >= 0; --bit) {
        unsigned C = T | (1u << bit);
        int c = 0;
#pragma unroll
        for (int i = 0; i < NPER/64; ++i)
            c += (int)__popcll(__ballot(u[i] < C));
        if (c < KNN) T = C;
    }

    unsigned lm = 0u, em = 0u;
#pragma unroll
    for (int i = 0; i < NPER/64; ++i) {
        lm |= (u[i] < T)  ? (1u << i) : 0u;
        em |= (u[i] == T) ? (1u << i) : 0u;
    }
    int nl = __popc(lm);
    int inc = nl;
#pragma unroll
    for (int off = 1; off < 64; off <<= 1) {
        int y = __shfl_up(inc, off);
        if (lane >= off) inc += y;
    }
    int excl = inc - nl;
    int total_less = __shfl(inc, 63);

    int* op = idx + (size_t)n * KNN;
    int slot = excl;
#pragma unroll
    for (int i = 0; i < NPER/64; ++i) {
        if (lm & (1u << i)) { op[slot] = base + i*64 + lane; ++slot; }
    }

    int need = KNN - total_less;
    int running = 0;
#pragma unroll
    for (int i = 0; i < NPER/64; ++i) {
        unsigned long long bal = __ballot((em >> i) & 1u);
        if (bal) {
            unsigned long long lt = bal & ((1ull << lane) - 1ull);
            int r = running + __popcll(lt);
            if (((em >> i) & 1u) && r < need) op[total_less + r] = base + i*64 + lane;
            running += (int)__popcll(bal);
        }
    }
}

// ---------------- kNN (small-D): block = 4 query points; LDS dist + radix select ----------
template<int D>
__global__ __launch_bounds__(256, 4) void knn4_kernel(const float* __restrict__ f, int stride,
                                                      const float* __restrict__ d2,
                                                      int* __restrict__ idx) {
    __shared__ float sdist[4][NPER];      // 32 KB
    __shared__ float sxi[4][(D+3)/4*4];
    __shared__ float sd2n[4];
    int t = threadIdx.x;
    int n0 = blockIdx.x * 4;
    int base = (n0 >> 11) << 11;

    if (t < 4*D) {
        int q = t / D, d = t - q*D;
        sxi[q][d] = f[(size_t)(n0 + q)*stride + d];
    }
    if (t < 4) sd2n[t] = d2[n0 + t];
    __syncthreads();

#pragma unroll 1
    for (int j = 0; j < NPER/256; ++j) {
        int ml = t + 256*j;
        int m = base + ml;
        const float* fm = f + (size_t)m*stride;
        float d2m = d2[m];
        float dot0 = 0.f, dot1 = 0.f, dot2 = 0.f, dot3 = 0.f;
#pragma unroll
        for (int d = 0; d < D; ++d) {
            float a = fm[d];
            dot0 += a*sxi[0][d];
            dot1 += a*sxi[1][d];
            dot2 += a*sxi[2][d];
            dot3 += a*sxi[3][d];
        }
        sdist[0][ml] = sd2n[0] + d2m - 2.f*dot0;
        sdist[1][ml] = sd2n[1] + d2m - 2.f*dot1;
        sdist[2][ml] = sd2n[2] + d2m - 2.f*dot2;
        sdist[3][ml] = sd2n[3] + d2m - 2.f*dot3;
    }
    __syncthreads();

    int w = t >> 6, lane = t & 63;
    select30(sdist[w], lane, base, n0 + w, idx);
}

// ---------------- 64-dim transpose + fused d2 ----------------
__global__ __launch_bounds__(256) void transpose64_kernel(const float* __restrict__ fin, int stride,
                                                          float* __restrict__ fT,
                                                          float* __restrict__ d2out) {
    __shared__ float tile[64][65];
    int t = threadIdx.x;
    int n0 = blockIdx.x * 64;
#pragma unroll
    for (int i = 0; i < 4; ++i) {
        int id = t + 256*i;
        int r = id >> 4, c4 = (id & 15) * 4;
        float4 v = *reinterpret_cast<const float4*>(&fin[(size_t)(n0 + r)*stride + c4]);
        tile[r][c4] = v.x; tile[r][c4+1] = v.y; tile[r][c4+2] = v.z; tile[r][c4+3] = v.w;
    }
    __syncthreads();
    if (t < 64) {
        float s = 0.f;
#pragma unroll
        for (int d = 0; d < 64; ++d) s += tile[t][d]*tile[t][d];
        d2out[n0 + t] = s;
    }
#pragma unroll
    for (int i = 0; i < 16; ++i) {
        int id = t + 256*i;
        int d = id >> 6, nn = id & 63;
        fT[(size_t)d * NPTS + n0 + nn] = tile[nn][d];
    }
}

// ---------------- kNN v8 (D=64): 8 queries/block (512 thr), thread owns 4 candidates.
// Candidate L2 traffic halves vs v6; per-pair accumulation order identical -> bit-exact. ----
__global__ void knn8_kernel(const float* __restrict__ fq, int qstride,
                            const float* __restrict__ fT,
                            const float* __restrict__ d2,
                            int* __restrict__ idx) {
    __shared__ float sdist[8][NPER];      // 64 KB
    __shared__ float sq[8][64];
    __shared__ float sd2n[8];
    int t = threadIdx.x;
    int n0 = blockIdx.x * 8;
    int base = (n0 >> 11) << 11;

    {
        int q = t >> 6, d = t & 63;
        sq[q][d] = fq[(size_t)(n0 + q)*qstride + d];
    }
    if (t < 8) sd2n[t] = d2[n0 + t];
    __syncthreads();

    float acc[8][4];
#pragma unroll
    for (int q = 0; q < 8; ++q)
#pragma unroll
        for (int j = 0; j < 4; ++j) acc[q][j] = 0.f;

    int cbase = base + 4*t;               // this thread's 4 consecutive candidates

#pragma unroll 2
    for (int dc = 0; dc < 16; ++dc) {
        int d0 = dc * 4;
        float qa[8][4];
#pragma unroll
        for (int q = 0; q < 8; ++q) {
            float4 qv = *reinterpret_cast<const float4*>(&sq[q][d0]);
            qa[q][0] = qv.x; qa[q][1] = qv.y; qa[q][2] = qv.z; qa[q][3] = qv.w;
        }
#pragma unroll
        for (int dd = 0; dd < 4; ++dd) {
            const float* cp = fT + (size_t)(d0 + dd) * NPTS + cbase;
            float4 cf = *reinterpret_cast<const float4*>(cp);
            float cv[4] = {cf.x, cf.y, cf.z, cf.w};
#pragma unroll
            for (int q = 0; q < 8; ++q) {
#pragma unroll
                for (int j = 0; j < 4; ++j)
                    acc[q][j] += cv[j]*qa[q][dd];
            }
        }
    }

    {
        float4 dmf = *reinterpret_cast<const float4*>(&d2[cbase]);
        float dmv[4] = {dmf.x, dmf.y, dmf.z, dmf.w};
#pragma unroll
        for (int q = 0; q < 8; ++q) {
            float dn = sd2n[q];
            float4 v;
            v.x = dn + dmv[0] - 2.f*acc[q][0];
            v.y = dn + dmv[1] - 2.f*acc[q][1];
            v.z = dn + dmv[2] - 2.f*acc[q][2];
            v.w = dn + dmv[3] - 2.f*acc[q][3];
            *reinterpret_cast<float4*>(&sdist[q][4*t]) = v;
        }
    }
    __syncthreads();

    int w = t >> 6, lane = t & 63;
    select30(sdist[w], lane, base, n0 + w, idx);
}

// ---------------- fused G & Gbase: one sF staging, two passes ----------------
template<int D>
__global__ __launch_bounds__(256) void gmatbase_kernel(const float* __restrict__ fin, int in_stride,
                                                       const float* __restrict__ wa,
                                                       const float* __restrict__ ba,
                                                       float* __restrict__ G,
                                                       float* __restrict__ Gb) {
    constexpr int DP = (D+7)/8*8;
    __shared__ float sF[64][DP];
    int t = threadIdx.x;
    int row0 = blockIdx.x * 64;
    for (int i = t; i < 64*D; i += 256) {
        int r = i / D, c = i - r*D;
        sF[r][c] = fin[(size_t)(row0 + r)*in_stride + c];
    }
    int w = t >> 6, lane = t & 63;
    {
        float wreg[D];
#pragma unroll
        for (int d = 0; d < D; ++d) wreg[d] = wa[(size_t)(D + d)*64 + lane];
        __syncthreads();
#pragma unroll 1
        for (int pi = 0; pi < 16; ++pi) {
            int p = w*16 + pi;
            float acc = 0.f;
            if constexpr (D % 4 == 0) {
#pragma unroll
                for (int d = 0; d < D; d += 4) {
                    float4 fv = *reinterpret_cast<const float4*>(&sF[p][d]);
                    acc += fv.x*wreg[d] + fv.y*wreg[d+1] + fv.z*wreg[d+2] + fv.w*wreg[d+3];
                }
            } else {
#pragma unroll
                for (int d = 0; d < D; ++d) acc += sF[p][d]*wreg[d];
            }
            G[(size_t)(row0 + p)*64 + lane] = acc;
        }
    }
    {
        float wreg[D];
#pragma unroll
        for (int d = 0; d < D; ++d)
            wreg[d] = wa[(size_t)d*64 + lane] - wa[(size_t)(D + d)*64 + lane];
        float bc = ba[lane];
#pragma unroll 1
        for (int pi = 0; pi < 16; ++pi) {
            int p = w*16 + pi;
            float acc = bc;
#pragma unroll
            for (int d = 0; d < D; ++d) acc += sF[p][d]*wreg[d];
            Gb[(size_t)(row0 + p)*64 + lane] = acc;
        }
    }
}

// ---------------- MFMA EdgeConv (emits fp32 + split-bf16 outputs) ----------------
__global__ __launch_bounds__(256) void edgemfma_kernel(
    const float* __restrict__ G, const float* __restrict__ Gbase,
    const int* __restrict__ idx,
    const ushort* __restrict__ wbTh, const ushort* __restrict__ wbTl,
    const float* __restrict__ bb,
    float* __restrict__ fout, int out_stride,
    ushort* __restrict__ fh, ushort* __restrict__ fl)
{
    __shared__ __align__(16) ushort sHh[128*72];
    __shared__ __align__(16) ushort sHl[128*72];
    __shared__ float sbase[4][64];
    int t = threadIdx.x;
    int n0 = blockIdx.x * 4;

    {
        int p = t >> 6, c = t & 63;
        sbase[p][c] = Gbase[(size_t)(n0 + p)*64 + c];
    }
    __syncthreads();

    {
        int r = t >> 1, c0 = (t & 1) * 32;
        int p = r >> 5, e = r & 31;
        int ecl = e < KNN ? e : (KNN - 1);
        int j = idx[(size_t)(n0 + p)*KNN + ecl];
        const float* gp = G + (size_t)j*64 + c0;
        const float* bp = &sbase[p][c0];
#pragma unroll
        for (int g = 0; g < 4; ++g) {
            float4 g0 = *reinterpret_cast<const float4*>(gp + 8*g);
            float4 g1 = *reinterpret_cast<const float4*>(gp + 8*g + 4);
            float4 b0 = *reinterpret_cast<const float4*>(bp + 8*g);
            float4 b1 = *reinterpret_cast<const float4*>(bp + 8*g + 4);
            float h[8] = {fmaxf(b0.x+g0.x,0.f), fmaxf(b0.y+g0.y,0.f),
                          fmaxf(b0.z+g0.z,0.f), fmaxf(b0.w+g0.w,0.f),
                          fmaxf(b1.x+g1.x,0.f), fmaxf(b1.y+g1.y,0.f),
                          fmaxf(b1.z+g1.z,0.f), fmaxf(b1.w+g1.w,0.f)};
            uint ph[4], pl[4];
#pragma unroll
            for (int i2 = 0; i2 < 4; ++i2) {
                ushort h0 = f2bf(h[2*i2]);
                ushort l0 = f2bf(h[2*i2] - bf2f(h0));
                ushort h1_ = f2bf(h[2*i2+1]);
                ushort l1 = f2bf(h[2*i2+1] - bf2f(h1_));
                ph[i2] = (uint)h0 | ((uint)h1_ << 16);
                pl[i2] = (uint)l0 | ((uint)l1 << 16);
            }
            *reinterpret_cast<uint4*>(&sHh[r*72 + c0 + 8*g]) = make_uint4(ph[0],ph[1],ph[2],ph[3]);
            *reinterpret_cast<uint4*>(&sHl[r*72 + c0 + 8*g]) = make_uint4(pl[0],pl[1],pl[2],pl[3]);
        }
    }
    __syncthreads();

    int lane = t & 63, w = t >> 6;
    int fr = lane & 15, fk = (lane >> 4) * 8;

    f32x4 acc[2][4];
#pragma unroll
    for (int mf = 0; mf < 2; ++mf)
#pragma unroll
        for (int nf = 0; nf < 4; ++nf) acc[mf][nf] = f32x4{0.f,0.f,0.f,0.f};

#pragma unroll
    for (int kk = 0; kk < 2; ++kk) {
        bf16x8 a0h = *reinterpret_cast<const bf16x8*>(&sHh[(w*32 + fr)*72 + kk*32 + fk]);
        bf16x8 a1h = *reinterpret_cast<const bf16x8*>(&sHh[(w*32 + 16 + fr)*72 + kk*32 + fk]);
        bf16x8 a0l = *reinterpret_cast<const bf16x8*>(&sHl[(w*32 + fr)*72 + kk*32 + fk]);
        bf16x8 a1l = *reinterpret_cast<const bf16x8*>(&sHl[(w*32 + 16 + fr)*72 + kk*32 + fk]);
#pragma unroll
        for (int nf = 0; nf < 4; ++nf) {
            bf16x8 bh = *reinterpret_cast<const bf16x8*>(&wbTh[(size_t)(nf*16 + fr)*64 + kk*32 + fk]);
            bf16x8 bl = *reinterpret_cast<const bf16x8*>(&wbTl[(size_t)(nf*16 + fr)*64 + kk*32 + fk]);
            acc[0][nf] = __builtin_amdgcn_mfma_f32_16x16x32_bf16(a0h, bh, acc[0][nf], 0,0,0);
            acc[0][nf] = __builtin_amdgcn_mfma_f32_16x16x32_bf16(a0h, bl, acc[0][nf], 0,0,0);
            acc[0][nf] = __builtin_amdgcn_mfma_f32_16x16x32_bf16(a0l, bh, acc[0][nf], 0,0,0);
            acc[1][nf] = __builtin_amdgcn_mfma_f32_16x16x32_bf16(a1h, bh, acc[1][nf], 0,0,0);
            acc[1][nf] = __builtin_amdgcn_mfma_f32_16x16x32_bf16(a1h, bl, acc[1][nf], 0,0,0);
            acc[1][nf] = __builtin_amdgcn_mfma_f32_16x16x32_bf16(a1l, bh, acc[1][nf], 0,0,0);
        }
    }

#pragma unroll
    for (int nf = 0; nf < 4; ++nf) {
        float vmax = -3.4e38f;
#pragma unroll
        for (int mf = 0; mf < 2; ++mf) {
#pragma unroll
            for (int j = 0; j < 4; ++j) {
                int lr = mf*16 + ((lane >> 4) << 2) + j;
                float v = acc[mf][nf][j];
                vmax = (lr < KNN) ? fmaxf(vmax, v) : vmax;
            }
        }
        vmax = fmaxf(vmax, __shfl_xor(vmax, 16));
        vmax = fmaxf(vmax, __shfl_xor(vmax, 32));
        if (lane < 16) {
            int c = nf*16 + lane;
            float v = vmax + bb[c];
            size_t o = (size_t)(n0 + w)*out_stride + c;
            fout[o] = v;
            ushort h = f2bf(v);
            fh[o] = h;
            fl[o] = f2bf(v - bf2f(h));
        }
    }
}

// ---------------- fused weight split: all 6 weight matrices in one dispatch ----------------
__global__ void wsplit_all_kernel(
    const float* __restrict__ hw1, ushort* __restrict__ w1h, ushort* __restrict__ w1l,
    const float* __restrict__ hw2, ushort* __restrict__ w2h, ushort* __restrict__ w2l,
    const float* __restrict__ hw3, ushort* __restrict__ w3h, ushort* __restrict__ w3l,
    const float* __restrict__ w1b, ushort* __restrict__ wb1h, ushort* __restrict__ wb1l,
    const float* __restrict__ w2b, ushort* __restrict__ wb2h, ushort* __restrict__ wb2l,
    const float* __restrict__ w3b, ushort* __restrict__ wb3h, ushort* __restrict__ wb3l)
{
    int gi = blockIdx.x * 256 + threadIdx.x;
    const float* w; ushort* hi; ushort* lo; int K, N, i;
    if (gi < 196608)      { w = hw1; hi = w1h; lo = w1l; K = 192;  N = 1024; i = gi; }
    else if (gi < 720896) { w = hw2; hi = w2h; lo = w2l; K = 1024; N = 512;  i = gi - 196608; }
    else if (gi < 786432) { w = hw3; hi = w3h; lo = w3l; K = 512;  N = 128;  i = gi - 720896; }
    else if (gi < 790528) { w = w1b; hi = wb1h; lo = wb1l; K = 64; N = 64;   i = gi - 786432; }
    else if (gi < 794624) { w = w2b; hi = wb2h; lo = wb2l; K = 64; N = 64;   i = gi - 790528; }
    else if (gi < 798720) { w = w3b; hi = wb3h; lo = wb3l; K = 64; N = 64;   i = gi - 794624; }
    else return;
    int n = i / K, k = i - n*K;
    float x = w[(size_t)k * N + n];
    ushort h = f2bf(x);
    hi[i] = h;
    lo[i] = f2bf(x - bf2f(h));
}

// ---------------- 128x128-tile split-bf16 GEMM: C = act(A @ B^T + bias) ----------------
template<bool RELU, bool SPLIT_OUT>
__global__ __launch_bounds__(256) void mlp_gemm2_kernel(
    const ushort* __restrict__ Ah, const ushort* __restrict__ Al, int K,
    const ushort* __restrict__ Bh, const ushort* __restrict__ Bl,
    const float* __restrict__ bias,
    float* __restrict__ C, ushort* __restrict__ Ch, ushort* __restrict__ Cl, int N)
{
    __shared__ __align__(16) ushort sAh[128*40];
    __shared__ __align__(16) ushort sAl[128*40];
    __shared__ __align__(16) ushort sBh[128*40];
    __shared__ __align__(16) ushort sBl[128*40];
    int t = threadIdx.x;
    int lane = t & 63, w = t >> 6;
    int row0 = blockIdx.x * 128;
    int n0   = blockIdx.y * 128;
    int wr = w & 1, wc = w >> 1;
    int fr = lane & 15, fq = lane >> 4, fk = fq * 8;
    int r = t >> 2, sg = (t & 3) * 8;

    f32x4 acc[4][4];
#pragma unroll
    for (int m = 0; m < 4; ++m)
#pragma unroll
        for (int n = 0; n < 4; ++n) acc[m][n] = f32x4{0.f,0.f,0.f,0.f};

    const int nk = K / 32;
#pragma unroll 1
    for (int kc = 0; kc < nk; ++kc) {
        int k0 = kc * 32;
        uint4 vah0 = *reinterpret_cast<const uint4*>(&Ah[(size_t)(row0 + r)*K + k0 + sg]);
        uint4 vah1 = *reinterpret_cast<const uint4*>(&Ah[(size_t)(row0 + r + 64)*K + k0 + sg]);
        uint4 val0 = *reinterpret_cast<const uint4*>(&Al[(size_t)(row0 + r)*K + k0 + sg]);
        uint4 val1 = *reinterpret_cast<const uint4*>(&Al[(size_t)(row0 + r + 64)*K + k0 + sg]);
        uint4 vbh0 = *reinterpret_cast<const uint4*>(&Bh[(size_t)(n0 + r)*K + k0 + sg]);
        uint4 vbh1 = *reinterpret_cast<const uint4*>(&Bh[(size_t)(n0 + r + 64)*K + k0 + sg]);
        uint4 vbl0 = *reinterpret_cast<const uint4*>(&Bl[(size_t)(n0 + r)*K + k0 + sg]);
        uint4 vbl1 = *reinterpret_cast<const uint4*>(&Bl[(size_t)(n0 + r + 64)*K + k0 + sg]);
        __syncthreads();
        *reinterpret_cast<uint4*>(&sAh[r*40 + sg]) = vah0;
        *reinterpret_cast<uint4*>(&sAh[(r+64)*40 + sg]) = vah1;
        *reinterpret_cast<uint4*>(&sAl[r*40 + sg]) = val0;
        *reinterpret_cast<uint4*>(&sAl[(r+64)*40 + sg]) = val1;
        *reinterpret_cast<uint4*>(&sBh[r*40 + sg]) = vbh0;
        *reinterpret_cast<uint4*>(&sBh[(r+64)*40 + sg]) = vbh1;
        *reinterpret_cast<uint4*>(&sBl[r*40 + sg]) = vbl0;
        *reinterpret_cast<uint4*>(&sBl[(r+64)*40 + sg]) = vbl1;
        __syncthreads();

        bf16x8 bh_[4], bl_[4];
#pragma unroll
        for (int n = 0; n < 4; ++n) {
            bh_[n] = *reinterpret_cast<const bf16x8*>(&sBh[(wc*64 + n*16 + fr)*40 + fk]);
            bl_[n] = *reinterpret_cast<const bf16x8*>(&sBl[(wc*64 + n*16 + fr)*40 + fk]);
        }
#pragma unroll
        for (int m = 0; m < 4; ++m) {
            bf16x8 ah_ = *reinterpret_cast<const bf16x8*>(&sAh[(wr*64 + m*16 + fr)*40 + fk]);
            bf16x8 al_ = *reinterpret_cast<const bf16x8*>(&sAl[(wr*64 + m*16 + fr)*40 + fk]);
#pragma unroll
            for (int n = 0; n < 4; ++n) {
                acc[m][n] = __builtin_amdgcn_mfma_f32_16x16x32_bf16(ah_, bh_[n], acc[m][n], 0,0,0);
                acc[m][n] = __builtin_amdgcn_mfma_f32_16x16x32_bf16(ah_, bl_[n], acc[m][n], 0,0,0);
                acc[m][n] = __builtin_amdgcn_mfma_f32_16x16x32_bf16(al_, bh_[n], acc[m][n], 0,0,0);
            }
        }
    }

#pragma unroll
    for (int n = 0; n < 4; ++n) {
        int ocol = n0 + wc*64 + n*16 + fr;
        float bc = bias[ocol];
#pragma unroll
        for (int m = 0; m < 4; ++m) {
            int orow = row0 + wr*64 + m*16 + fq*4;
#pragma unroll
            for (int j = 0; j < 4; ++j) {
                float v = acc[m][n][j] + bc;
                if (RELU) v = fmaxf(v, 0.f);
                if (SPLIT_OUT) {
                    ushort h = f2bf(v);
                    Ch[(size_t)(orow + j)*N + ocol] = h;
                    Cl[(size_t)(orow + j)*N + ocol] = f2bf(v - bf2f(h));
                } else {
                    C[(size_t)(orow + j)*N + ocol] = v;
                }
            }
        }
    }
}

// ---------------- 64x128-tile variant (for low-grid output layer) ----------------
template<bool RELU>
__global__ __launch_bounds__(256) void mlp_gemm3_kernel(
    const ushort* __restrict__ Ah, const ushort* __restrict__ Al, int K,
    const ushort* __restrict__ Bh, const ushort* __restrict__ Bl,
    const float* __restrict__ bias,
    float* __restrict__ C, int N)
{
    __shared__ __align__(16) ushort sAh[64*40];
    __shared__ __align__(16) ushort sAl[64*40];
    __shared__ __align__(16) ushort sBh[128*40];
    __shared__ __align__(16) ushort sBl[128*40];
    int t = threadIdx.x;
    int lane = t & 63, w = t >> 6;
    int row0 = blockIdx.x * 64;
    int n0   = blockIdx.y * 128;
    int wr = w & 1, wc = w >> 1;
    int fr = lane & 15, fq = lane >> 4, fk = fq * 8;
    int r = t >> 2, sg = (t & 3) * 8;

    f32x4 acc[2][4];
#pragma unroll
    for (int m = 0; m < 2; ++m)
#pragma unroll
        for (int n = 0; n < 4; ++n) acc[m][n] = f32x4{0.f,0.f,0.f,0.f};

    const int nk = K / 32;
#pragma unroll 1
    for (int kc = 0; kc < nk; ++kc) {
        int k0 = kc * 32;
        uint4 vah0 = *reinterpret_cast<const uint4*>(&Ah[(size_t)(row0 + r)*K + k0 + sg]);
        uint4 val0 = *reinterpret_cast<const uint4*>(&Al[(size_t)(row0 + r)*K + k0 + sg]);
        uint4 vbh0 = *reinterpret_cast<const uint4*>(&Bh[(size_t)(n0 + r)*K + k0 + sg]);
        uint4 vbh1 = *reinterpret_cast<const uint4*>(&Bh[(size_t)(n0 + r + 64)*K + k0 + sg]);
        uint4 vbl0 = *reinterpret_cast<const uint4*>(&Bl[(size_t)(n0 + r)*K + k0 + sg]);
        uint4 vbl1 = *reinterpret_cast<const uint4*>(&Bl[(size_t)(n0 + r + 64)*K + k0 + sg]);
        __syncthreads();
        *reinterpret_cast<uint4*>(&sAh[r*40 + sg]) = vah0;
        *reinterpret_cast<uint4*>(&sAl[r*40 + sg]) = val0;
        *reinterpret_cast<uint4*>(&sBh[r*40 + sg]) = vbh0;
        *reinterpret_cast<uint4*>(&sBh[(r+64)*40 + sg]) = vbh1;
        *reinterpret_cast<uint4*>(&sBl[r*40 + sg]) = vbl0;
        *reinterpret_cast<uint4*>(&sBl[(r+64)*40 + sg]) = vbl1;
        __syncthreads();

        bf16x8 bh_[4], bl_[4];
#pragma unroll
        for (int n = 0; n < 4; ++n) {
            bh_[n] = *reinterpret_cast<const bf16x8*>(&sBh[(wc*64 + n*16 + fr)*40 + fk]);
            bl_[n] = *reinterpret_cast<const bf16x8*>(&sBl[(wc*64 + n*16 + fr)*40 + fk]);
        }
#pragma unroll
        for (int m = 0; m < 2; ++m) {
            bf16x8 ah_ = *reinterpret_cast<const bf16x8*>(&sAh[(wr*32 + m*16 + fr)*40 + fk]);
            bf16x8 al_ = *reinterpret_cast<const bf16x8*>(&sAl[(wr*32 + m*16 + fr)*40 + fk]);
#pragma unroll
            for (int n = 0; n < 4; ++n) {
                acc[m][n] = __builtin_amdgcn_mfma_f32_16x16x32_bf16(ah_, bh_[n], acc[m][n], 0,0,0);
                acc[m][n] = __builtin_amdgcn_mfma_f32_16x16x32_bf16(ah_, bl_[n], acc[m][n], 0,0,0);
                acc[m][n] = __builtin_amdgcn_mfma_f32_16x16x32_bf16(al_, bh_[n], acc[m][n], 0,0,0);
            }
        }
    }

#pragma unroll
    for (int n = 0; n < 4; ++n) {
        int ocol = n0 + wc*64 + n*16 + fr;
        float bc = bias[ocol];
#pragma unroll
        for (int m = 0; m < 2; ++m) {
            int orow = row0 + wr*32 + m*16 + fq*4;
#pragma unroll
            for (int j = 0; j < 4; ++j) {
                float v = acc[m][n][j] + bc;
                if (RELU) v = fmaxf(v, 0.f);
                C[(size_t)(orow + j)*N + ocol] = v;
            }
        }
    }
}

extern "C" void kernel_launch(void* const* d_in, const int* in_sizes, int n_in,
                              void* d_out, int out_size, void* d_ws, size_t ws_size,
                              hipStream_t stream) {
    (void)in_sizes; (void)n_in; (void)out_size;
    const float* x   = (const float*)d_in[0];
    const float* pos = (const float*)d_in[1];
    const float* w1a = (const float*)d_in[2];
    const float* b1a = (const float*)d_in[3];
    const float* w1b = (const float*)d_in[4];
    const float* b1b = (const float*)d_in[5];
    const float* w2a = (const float*)d_in[6];
    const float* b2a = (const float*)d_in[7];
    const float* w2b = (const float*)d_in[8];
    const float* b2b = (const float*)d_in[9];
    const float* w3a = (const float*)d_in[10];
    const float* b3a = (const float*)d_in[11];
    const float* w3b = (const float*)d_in[12];
    const float* b3b = (const float*)d_in[13];
    const float* hw1 = (const float*)d_in[14];
    const float* hb1 = (const float*)d_in[15];
    const float* hw2 = (const float*)d_in[16];
    const float* hb2 = (const float*)d_in[17];
    const float* hw3 = (const float*)d_in[18];
    const float* hb3 = (const float*)d_in[19];
    float* out = (float*)d_out;

    float* ws = (float*)d_ws;
    float* x0   = ws;                                  // 98304
    float* feat = ws + 98304;                          // 3145728
    float* d2b  = ws + 3244032;                        // 16384
    int*   idxb = (int*)(ws + 3260416);                // 491520
    float* G    = ws + 3751936;                        // 1048576 (fT before gmatbase, G after)
    ushort* w1h = (ushort*)(ws + 4800512);
    ushort* w1l = (ushort*)(ws + 4898816);
    ushort* w2h = (ushort*)(ws + 4997120);
    ushort* w2l = (ushort*)(ws + 5259264);
    ushort* w3h = (ushort*)(ws + 5521408);
    ushort* w3l = (ushort*)(ws + 5554176);
    ushort* wb1h = (ushort*)(ws + 5586944);
    ushort* wb1l = (ushort*)(ws + 5588992);
    ushort* wb2h = (ushort*)(ws + 5591040);
    ushort* wb2l = (ushort*)(ws + 5593088);
    ushort* wb3h = (ushort*)(ws + 5595136);
    ushort* wb3l = (ushort*)(ws + 5597184);
    float* Gbase = ws + 5599232;                       // 1048576 -> 6647808
    ushort* fAh  = (ushort*)(ws + 6647808);            // -> 8220672
    ushort* fAl  = (ushort*)(ws + 8220672);            // -> 9793536
    const size_t base_units = 9793536;

    float* fT = G;

    int ns = 0;
    {
        const int cands[5] = {1, 2, 4, 8, 16};
        for (int ci = 0; ci < 5; ++ci) {
            int c = cands[ci];
            size_t need = (base_units + (size_t)(NPTS / c) * 1536) * 4;
            if (need <= ws_size) { ns = c; break; }
        }
    }

    wsplit_all_kernel<<<(798720 + 255)/256, 256, 0, stream>>>(
        hw1, w1h, w1l, hw2, w2h, w2l, hw3, w3h, w3l,
        w1b, wb1h, wb1l, w2b, wb2h, wb2l, w3b, wb3h, wb3l);

    concat_d2_kernel<<<NPTS/256, 256, 0, stream>>>(x, pos, x0, d2b);

    // ---- layer 1 (D=6) ----
    knn4_kernel<6><<<NPTS/4, 256, 0, stream>>>(x0, 6, d2b, idxb);
    gmatbase_kernel<6><<<NPTS/64, 256, 0, stream>>>(x0, 6, w1a, b1a, G, Gbase);
    edgemfma_kernel<<<NPTS/4, 256, 0, stream>>>(G, Gbase, idxb, wb1h, wb1l, b1b,
                                                feat, 192, fAh, fAl);

    // ---- layer 2 (D=64) ----
    transpose64_kernel<<<NPTS/64, 256, 0, stream>>>(feat, 192, fT, d2b);
    knn8_kernel<<<NPTS/8, 512, 0, stream>>>(feat, 192, fT, d2b, idxb);
    gmatbase_kernel<64><<<NPTS/64, 256, 0, stream>>>(feat, 192, w2a, b2a, G, Gbase);
    edgemfma_kernel<<<NPTS/4, 256, 0, stream>>>(G, Gbase, idxb, wb2h, wb2l, b2b,
                                                feat + 64, 192, fAh + 64, fAl + 64);

    // ---- layer 3 (D=64) ----
    transpose64_kernel<<<NPTS/64, 256, 0, stream>>>(feat + 64, 192, fT, d2b);
    knn8_kernel<<<NPTS/8, 512, 0, stream>>>(feat + 64, 192, fT, d2b, idxb);
    gmatbase_kernel<64><<<NPTS/64, 256, 0, stream>>>(feat + 64, 192, w3a, b3a, G, Gbase);
    edgemfma_kernel<<<NPTS/4, 256, 0, stream>>>(G, Gbase, idxb, wb3h, wb3l, b3b,
                                                feat + 128, 192, fAh + 128, fAl + 128);

    // ---- head ----
    if (ns > 0) {
        int Ms = NPTS / ns;
        ushort* h1h = (ushort*)(ws + base_units);
        ushort* h1l = h1h + (size_t)Ms * 1024;
        ushort* h2h = (ushort*)(ws + base_units + (size_t)Ms * 1024);
        ushort* h2l = h2h + (size_t)Ms * 512;
        for (int s = 0; s < ns; ++s) {
            const ushort* Ash = fAh + (size_t)s * Ms * 192;
            const ushort* Asl = fAl + (size_t)s * Ms * 192;
            float* outs = out + (size_t)s * Ms * 128;
            mlp_gemm2_kernel<true, true ><<<dim3(Ms/128, 1024/128), 256, 0, stream>>>(
                Ash, Asl, 192, w1h, w1l, hb1, nullptr, h1h, h1l, 1024);
            mlp_gemm2_kernel<true, true ><<<dim3(Ms/128,  512/128), 256, 0, stream>>>(
                h1h, h1l, 1024, w2h, w2l, hb2, nullptr, h2h, h2l, 512);
            mlp_gemm3_kernel<false><<<dim3(Ms/64, 1), 256, 0, stream>>>(
                h2h, h2l, 512, w3h, w3l, hb3, outs, 128);
        }
    }
}